// Round 8
// baseline (345.428 us; speedup 1.0000x reference)
//
#include <hip/hip_runtime.h>
#include <hip/hip_bf16.h>

#define IN_DIM 128
#define HID_DIM 256
#define OUT_DIM 40
#define SCAN_CHUNK 2048

typedef __attribute__((ext_vector_type(8))) __bf16 bf16x8;
typedef __attribute__((ext_vector_type(4))) float f32x4;

__device__ inline ushort f2bf(float f) {
    uint u = __builtin_bit_cast(uint, f);
    u = (u + 0x7fff + ((u >> 16) & 1)) >> 16;
    return (ushort)u;
}
__device__ inline float bfl(uint u) { return __builtin_bit_cast(float, u << 16); }
__device__ inline float bfh(uint u) { return __builtin_bit_cast(float, u & 0xffff0000u); }

// async global->LDS, 16B per lane. dest base must be wave-uniform; HW adds lane*16.
__device__ inline void gload_lds16(const ushort* g, ushort* l) {
    __builtin_amdgcn_global_load_lds((const __attribute__((address_space(1))) void*)g,
                                     (__attribute__((address_space(3))) void*)l, 16, 0, 0);
}

// bijective XCD-chunked swizzle (m204)
__device__ inline int xcd_swizzle(int b, int G) {
    int q = G >> 3, r = G & 7;
    int xcd = b & 7, j = b >> 3;
    return (xcd < r ? xcd * (q + 1) : r * (q + 1) + (xcd - r) * q) + j;
}

// ---------------- fused prep: cvt_x + cvt_weights + hist (independent jobs) ----------------
__global__ __launch_bounds__(256) void prep_kernel(
    const float* __restrict__ x, ushort* __restrict__ xb, int n4, int XB,
    const float* __restrict__ Wl1, const float* __restrict__ Wr1,
    const float* __restrict__ Wl2, const float* __restrict__ Wr2,
    const float* __restrict__ Wl3, const float* __restrict__ Wr3,
    ushort* __restrict__ o1l, ushort* __restrict__ o1r,
    ushort* __restrict__ o2l, ushort* __restrict__ o2r,
    ushort* __restrict__ o3l, ushort* __restrict__ o3r, int WB,
    const int* __restrict__ dst, int* __restrict__ cnt, int E) {
    int b = blockIdx.x;
    if (b < XB) {
        int i = b * 256 + threadIdx.x;
        if (i < n4) {
            float4 v = ((const float4*)x)[i];
            uint2 o;
            o.x = (uint)f2bf(v.x) | ((uint)f2bf(v.y) << 16);
            o.y = (uint)f2bf(v.z) | ((uint)f2bf(v.w) << 16);
            ((uint2*)xb)[i] = o;
        }
        return;
    }
    b -= XB;
    if (b < WB) {
        int idx = b * 256 + threadIdx.x;
        if (idx < 32768) {
            // W1: K=128, NK=4. idx bits: j3 | ln4 | quad2 | kk2 | ct2 | cb2
            int j = idx & 7, ln = (idx >> 3) & 15, quad = (idx >> 7) & 3;
            int kk = (idx >> 9) & 3, ct = (idx >> 11) & 3, cb = idx >> 13;
            int o = cb * 64 + ct * 16 + ln;
            int k = kk * 32 + quad * 8 + j;
            o1l[idx] = f2bf(Wl1[o * 128 + k]);
            o1r[idx] = f2bf(Wr1[o * 128 + k]);
            return;
        }
        idx -= 32768;
        if (idx < 65536) {
            // W2: K=256, NK=8. idx bits: j3 | ln4 | quad2 | kk3 | ct2 | cb2
            int j = idx & 7, ln = (idx >> 3) & 15, quad = (idx >> 7) & 3;
            int kk = (idx >> 9) & 7, ct = (idx >> 12) & 3, cb = idx >> 14;
            int o = cb * 64 + ct * 16 + ln;
            int k = kk * 32 + quad * 8 + j;
            o2l[idx] = f2bf(Wl2[o * 256 + k]);
            o2r[idx] = f2bf(Wr2[o * 256 + k]);
            return;
        }
        idx -= 65536;
        if (idx < 48 * 256) {
            int row = idx >> 8;
            int col = idx & 255;
            ushort vl = 0, vr = 0;
            if (row < OUT_DIM) {
                vl = f2bf(Wl3[row * 256 + col]);
                vr = f2bf(Wr3[row * 256 + col]);
            }
            o3l[idx] = vl;
            o3r[idx] = vr;
        }
        return;
    }
    b -= WB;
    int e = b * 256 + threadIdx.x;
    if (e < E) atomicAdd(&cnt[dst[e]], 1);
}

// ---------------- CSR scan ----------------
__global__ __launch_bounds__(256) void scan_pass1(const int* __restrict__ cnt,
                                                  int* __restrict__ bsum, int N) {
    __shared__ int red[256];
    const int base = blockIdx.x * SCAN_CHUNK;
    int s = 0;
    for (int i = threadIdx.x; i < SCAN_CHUNK; i += 256) {
        int idx = base + i;
        if (idx < N) s += cnt[idx];
    }
    red[threadIdx.x] = s;
    __syncthreads();
    for (int o = 128; o > 0; o >>= 1) {
        if (threadIdx.x < o) red[threadIdx.x] += red[threadIdx.x + o];
        __syncthreads();
    }
    if (threadIdx.x == 0) bsum[blockIdx.x] = red[0];
}

__global__ __launch_bounds__(256) void scan_pass3(const int* __restrict__ cnt,
                                                  const int* __restrict__ bsum,
                                                  int* __restrict__ rowptr,
                                                  int* __restrict__ cursor,
                                                  float* __restrict__ inv,
                                                  int N, int E, int SB) {
    __shared__ int ls[256];
    __shared__ int boff;
    if (threadIdx.x == 0) {
        int r = 0;
        for (int i = 0; i < blockIdx.x; ++i) r += bsum[i];
        boff = r;
    }
    const int tbase = blockIdx.x * SCAN_CHUNK + threadIdx.x * 8;
    int c[8];
    int s = 0;
#pragma unroll
    for (int j = 0; j < 8; ++j) {
        int idx = tbase + j;
        c[j] = (idx < N) ? cnt[idx] : 0;
        s += c[j];
    }
    ls[threadIdx.x] = s;
    __syncthreads();
    for (int o = 1; o < 256; o <<= 1) {
        int u = (threadIdx.x >= o) ? ls[threadIdx.x - o] : 0;
        __syncthreads();
        ls[threadIdx.x] += u;
        __syncthreads();
    }
    int run = boff + ls[threadIdx.x] - s;
#pragma unroll
    for (int j = 0; j < 8; ++j) {
        int idx = tbase + j;
        if (idx < N) {
            rowptr[idx] = run;
            cursor[idx] = run;
            inv[idx] = 1.0f / fmaxf((float)c[j], 1.0f);
            run += c[j];
        }
    }
    if (blockIdx.x == 0 && threadIdx.x == 0) rowptr[N] = E;
}

__global__ __launch_bounds__(256) void fill_kernel(const int* __restrict__ src,
                                                   const int* __restrict__ dst,
                                                   int* __restrict__ cursor,
                                                   int* __restrict__ srcs, int E) {
    int e = blockIdx.x * 256 + threadIdx.x;
    if (e < E) {
        int pos = atomicAdd(&cursor[dst[e]], 1);
        srcs[pos] = src[e];
    }
}

// ---------------- gather mean (R18: multi-node/wave, 16B/lane uint4 loads) ----------------
template <int D>
__global__ __launch_bounds__(256) void gather_mean_bf(const ushort* __restrict__ feat,
                                                      const int* __restrict__ rowptr,
                                                      const int* __restrict__ srcs,
                                                      const float* __restrict__ inv,
                                                      ushort* __restrict__ out, int N) {
    constexpr int LPN = D / 8;       // lanes per node (16B per lane)
    constexpr int NPW = 64 / LPN;    // nodes per wave: 2 (D=256) or 4 (D=128)
    constexpr int NPB = 4 * NPW;     // nodes per block
    const int wave = threadIdx.x >> 6;
    const int lane = threadIdx.x & 63;
    const int sub = lane / LPN;
    const int sl = lane % LPN;
    const int n = blockIdx.x * NPB + wave * NPW + sub;
    const bool alive = n < N;
    const int beg = alive ? rowptr[n] : 0;
    const int end = alive ? rowptr[n + 1] : 0;
    const int col = sl * 8;

    float a0 = 0.f, a1 = 0.f, a2 = 0.f, a3 = 0.f;
    float a4 = 0.f, a5 = 0.f, a6 = 0.f, a7 = 0.f;
    int e = beg;
    for (; e + 3 < end; e += 4) {
        uint4 q[4];
#pragma unroll
        for (int j = 0; j < 4; ++j)
            q[j] = *(const uint4*)&feat[(long long)srcs[e + j] * D + col];
#pragma unroll
        for (int j = 0; j < 4; ++j) {
            a0 += bfl(q[j].x); a1 += bfh(q[j].x);
            a2 += bfl(q[j].y); a3 += bfh(q[j].y);
            a4 += bfl(q[j].z); a5 += bfh(q[j].z);
            a6 += bfl(q[j].w); a7 += bfh(q[j].w);
        }
    }
    for (; e < end; ++e) {
        uint4 q = *(const uint4*)&feat[(long long)srcs[e] * D + col];
        a0 += bfl(q.x); a1 += bfh(q.x);
        a2 += bfl(q.y); a3 += bfh(q.y);
        a4 += bfl(q.z); a5 += bfh(q.z);
        a6 += bfl(q.w); a7 += bfh(q.w);
    }
    if (alive) {
        const float sc = inv[n];
        uint4 o;
        o.x = (uint)f2bf(a0 * sc) | ((uint)f2bf(a1 * sc) << 16);
        o.y = (uint)f2bf(a2 * sc) | ((uint)f2bf(a3 * sc) << 16);
        o.z = (uint)f2bf(a4 * sc) | ((uint)f2bf(a5 * sc) << 16);
        o.w = (uint)f2bf(a6 * sc) | ((uint)f2bf(a7 * sc) << 16);
        *(uint4*)&out[(long long)n * D + col] = o;
    }
}

// ---------------- MFMA SAGE GEMM (R20: R17 structure, launch_bounds (512,2)) --------------
// Identical to R17 (measured best 46.2us) EXCEPT __launch_bounds__(512,2): VGPR cap 64->128
// so the compiler can HOLD acc[2][4] (32 VGPR) + areg[8][2] (64 VGPR) + addresses and honor
// the source-order prefetch (16 A loads in flight before the barrier; phase-1 A reloads
// issued under phase-0 MFMAs). Theory: all prior rounds were latency-serialized because the
// VGPR cap forced the compiler to sink A loads to their use points.
template <int K, bool RELU, bool OUTBF>
__global__ __launch_bounds__(512, 2) void sage_gemm_mfma(const ushort* __restrict__ Amean,
                                                         const ushort* __restrict__ Aself,
                                                         const ushort* __restrict__ Wl,
                                                         const float* __restrict__ bias,
                                                         const ushort* __restrict__ Wr,
                                                         void* __restrict__ outv, int N, int O,
                                                         int G) {
    constexpr int NK = K / 32;            // k-steps per phase
    constexpr int TILE = 64 * K;          // ushorts per (cb, matrix) W tile
    constexpr int CHUNKS = TILE / 512;    // 1KB chunks (64 lanes x 16B)
    __shared__ __align__(16) ushort Ws[2 * TILE];  // K=256: 64KB, K=128: 32KB

    const int tid = threadIdx.x;
    const int wave = tid >> 6;   // 0..7
    const int lane = tid & 63;
    const int ln = lane & 15;
    const int quad = lane >> 4;

    const int wid = xcd_swizzle(blockIdx.x, G);
    const int cb = wid & 3;            // col-block: fast axis within an XCD chunk
    const int bm0 = (wid >> 2) * 256;  // row-block (256 rows: 8 waves x 32)

    // ---- stage BOTH W tiles once (frag-packed => linear LDS, conflict-free) ----
    {
        const ushort* gl = Wl + (size_t)cb * TILE;
        const ushort* gr = Wr + (size_t)cb * TILE;
#pragma unroll
        for (int c = wave; c < CHUNKS; c += 8) {
            gload_lds16(gl + c * 512 + lane * 8, &Ws[c * 512]);
            gload_lds16(gr + c * 512 + lane * 8, &Ws[TILE + c * 512]);
        }
    }

    int arow[2];
#pragma unroll
    for (int rt = 0; rt < 2; ++rt) {
        int r = bm0 + wave * 32 + rt * 16 + ln;
        arow[rt] = min(r, N - 1);
    }

    // ---- phase-0 A fragments, issued while gll is in flight ----
    bf16x8 areg[NK][2];
#pragma unroll
    for (int kk = 0; kk < NK; ++kk)
#pragma unroll
        for (int rt = 0; rt < 2; ++rt)
            areg[kk][rt] = *(const bf16x8*)&Amean[(long long)arow[rt] * K + kk * 32 + quad * 8];

    f32x4 acc[2][4] = {};
    __syncthreads();  // ONE barrier: drains gll + phase-0 areg

    // ---- phase 0 MFMA; after consuming areg[kk], reload it from Aself for phase 1 ----
#pragma unroll
    for (int kk = 0; kk < NK; ++kk) {
#pragma unroll
        for (int ct = 0; ct < 4; ++ct) {
            bf16x8 b = *(const bf16x8*)&Ws[((ct * NK + kk) * 64 + lane) * 8];
#pragma unroll
            for (int rt = 0; rt < 2; ++rt)
                acc[rt][ct] = __builtin_amdgcn_mfma_f32_16x16x32_bf16(areg[kk][rt], b, acc[rt][ct], 0, 0, 0);
        }
#pragma unroll
        for (int rt = 0; rt < 2; ++rt)
            areg[kk][rt] = *(const bf16x8*)&Aself[(long long)arow[rt] * K + kk * 32 + quad * 8];
    }

    // ---- phase 1 MFMA (Wr half of LDS) ----
#pragma unroll
    for (int kk = 0; kk < NK; ++kk) {
#pragma unroll
        for (int ct = 0; ct < 4; ++ct) {
            bf16x8 b = *(const bf16x8*)&Ws[TILE + ((ct * NK + kk) * 64 + lane) * 8];
#pragma unroll
            for (int rt = 0; rt < 2; ++rt)
                acc[rt][ct] = __builtin_amdgcn_mfma_f32_16x16x32_bf16(areg[kk][rt], b, acc[rt][ct], 0, 0, 0);
        }
    }

#pragma unroll
    for (int rt = 0; rt < 2; ++rt) {
        int rbase = bm0 + wave * 32 + rt * 16 + quad * 4;
#pragma unroll
        for (int ct = 0; ct < 4; ++ct) {
            int col = cb * 64 + ct * 16 + ln;
            if (col >= O) continue;
            float bv = bias[col];
#pragma unroll
            for (int r = 0; r < 4; ++r) {
                int row = rbase + r;
                if (row >= N) continue;
                float v = acc[rt][ct][r] + bv;
                if (RELU) v = fmaxf(v, 0.f);
                if (OUTBF)
                    ((ushort*)outv)[(long long)row * O + col] = f2bf(v);
                else
                    ((float*)outv)[(long long)row * O + col] = v;
            }
        }
    }
}

// ---------------- layer-3 pre-aggregation GEMM: P = A@Wl^T (bf16), S = A@Wr^T (fp32) ----------------
template <int K>
__global__ __launch_bounds__(256, 3) void sage_gemm_pre(const ushort* __restrict__ A0,
                                                        const ushort* __restrict__ Wl,
                                                        const ushort* __restrict__ Wr,
                                                        ushort* __restrict__ P,
                                                        float* __restrict__ S, int N, int O) {
    constexpr int KP = 2 * K + 8;
    constexpr int NK = K / 32;  // 8
    __shared__ __align__(16) ushort Ws[48 * KP];  // 49 KB

    const int tid = threadIdx.x;
    const int wave = tid >> 6;
    const int lane = tid & 63;
    const int ln = lane & 15;
    const int quad = lane >> 4;
    const int bm0 = blockIdx.x * 64;

    const int arow = min(bm0 + wave * 16 + ln, N - 1);

#pragma unroll
    for (int i = tid; i < 48 * (K / 8); i += 256) {
        int row = i / (K / 8);
        int c8 = (i % (K / 8)) * 8;
        *(ulonglong2*)&Ws[row * KP + c8] =
            *(const ulonglong2*)&Wl[(long long)row * K + c8];
        *(ulonglong2*)&Ws[row * KP + K + c8] =
            *(const ulonglong2*)&Wr[(long long)row * K + c8];
    }
    __syncthreads();

#pragma unroll
    for (int phase = 0; phase < 2; ++phase) {
        f32x4 acc[3] = {};
#pragma unroll
        for (int kk = 0; kk < NK; ++kk) {
            bf16x8 a = *(const bf16x8*)&A0[(long long)arow * K + kk * 32 + quad * 8];
#pragma unroll
            for (int ct = 0; ct < 3; ++ct) {
                bf16x8 b = *(const bf16x8*)&Ws[(ct * 16 + ln) * KP + phase * K + kk * 32 + quad * 8];
                acc[ct] = __builtin_amdgcn_mfma_f32_16x16x32_bf16(a, b, acc[ct], 0, 0, 0);
            }
        }
        int rbase = bm0 + wave * 16 + quad * 4;
#pragma unroll
        for (int ct = 0; ct < 3; ++ct) {
            int col = ct * 16 + ln;
            if (col >= O) continue;
#pragma unroll
            for (int r = 0; r < 4; ++r) {
                int row = rbase + r;
                if (row >= N) continue;
                if (phase == 0)
                    P[(long long)row * O + col] = f2bf(acc[ct][r]);
                else
                    S[(long long)row * O + col] = acc[ct][r];
            }
        }
    }
}

// ---------------- fused mean-agg(D=40) + self + bias + log_softmax ----------------
__global__ __launch_bounds__(256) void agg_bias_lsm(const ushort* __restrict__ P,
                                                    const float* __restrict__ S,
                                                    const float* __restrict__ bias,
                                                    const int* __restrict__ rowptr,
                                                    const int* __restrict__ srcs,
                                                    const float* __restrict__ inv,
                                                    float* __restrict__ out, int N) {
    const int wave = threadIdx.x >> 6;
    const int lane = threadIdx.x & 63;
    const int n = blockIdx.x * 4 + wave;
    if (n >= N) return;
    const int beg = rowptr[n];
    const int end = rowptr[n + 1];
    const bool act = lane < OUT_DIM;
    const int cidx = act ? lane : 0;

    float acc = 0.f;
    int e = beg;
    for (; e + 3 < end; e += 4) {
        int s0 = srcs[e], s1 = srcs[e + 1], s2 = srcs[e + 2], s3 = srcs[e + 3];
        float v0 = __builtin_bit_cast(float, (uint)P[(long long)s0 * OUT_DIM + cidx] << 16);
        float v1 = __builtin_bit_cast(float, (uint)P[(long long)s1 * OUT_DIM + cidx] << 16);
        float v2 = __builtin_bit_cast(float, (uint)P[(long long)s2 * OUT_DIM + cidx] << 16);
        float v3 = __builtin_bit_cast(float, (uint)P[(long long)s3 * OUT_DIM + cidx] << 16);
        acc += (v0 + v1) + (v2 + v3);
    }
    for (; e < end; ++e)
        acc += __builtin_bit_cast(float, (uint)P[(long long)srcs[e] * OUT_DIM + cidx] << 16);

    float v = act ? (acc * inv[n] + S[(long long)n * OUT_DIM + lane] + bias[lane]) : -INFINITY;
    float m = v;
#pragma unroll
    for (int o = 32; o > 0; o >>= 1) m = fmaxf(m, __shfl_xor(m, o, 64));
    float ex = act ? expf(v - m) : 0.f;
    float sm = ex;
#pragma unroll
    for (int o = 32; o > 0; o >>= 1) sm += __shfl_xor(sm, o, 64);
    float ls = logf(sm);
    if (act) out[(long long)n * OUT_DIM + lane] = v - m - ls;
}

extern "C" void kernel_launch(void* const* d_in, const int* in_sizes, int n_in,
                              void* d_out, int out_size, void* d_ws, size_t ws_size,
                              hipStream_t stream) {
    const float* x   = (const float*)d_in[0];
    const int*   ei  = (const int*)d_in[1];
    const float* Wl1 = (const float*)d_in[2];
    const float* bl1 = (const float*)d_in[3];
    const float* Wr1 = (const float*)d_in[4];
    const float* Wl2 = (const float*)d_in[5];
    const float* bl2 = (const float*)d_in[6];
    const float* Wr2 = (const float*)d_in[7];
    const float* Wl3 = (const float*)d_in[8];
    const float* bl3 = (const float*)d_in[9];
    const float* Wr3 = (const float*)d_in[10];
    float* out = (float*)d_out;

    const int N = in_sizes[0] / IN_DIM;  // 50000
    const int E = in_sizes[1] / 2;       // 600000
    const int* src = ei;
    const int* dst = ei + E;

    // ---- workspace layout ----
    char* w = (char*)d_ws;
    size_t off = 0;
    auto alloc = [&](size_t bytes) {
        void* p = w + off;
        off = (off + bytes + 255) & ~(size_t)255;
        return p;
    };
    ushort* xb   = (ushort*)alloc((size_t)N * IN_DIM * 2);
    ushort* M    = (ushort*)alloc((size_t)N * HID_DIM * 2);
    ushort* H1   = (ushort*)alloc((size_t)N * HID_DIM * 2);
    ushort* H2   = (ushort*)alloc((size_t)N * HID_DIM * 2);
    ushort* P3   = (ushort*)alloc((size_t)N * OUT_DIM * 2);
    float*  S3   = (float*)alloc((size_t)N * OUT_DIM * 4);
    float*  inv  = (float*)alloc((size_t)N * 4);
    int*    cnt  = (int*)alloc((size_t)N * 4);
    int*    rowptr = (int*)alloc((size_t)(N + 1) * 4);
    int*    cursor = (int*)alloc((size_t)N * 4);
    int*    srcs = (int*)alloc((size_t)E * 4);
    int*    bsum = (int*)alloc(256 * 4);
    ushort* Wl1b = (ushort*)alloc(256 * 128 * 2);
    ushort* Wr1b = (ushort*)alloc(256 * 128 * 2);
    ushort* Wl2b = (ushort*)alloc(256 * 256 * 2);
    ushort* Wr2b = (ushort*)alloc(256 * 256 * 2);
    ushort* Wl3b = (ushort*)alloc(48 * 256 * 2);
    ushort* Wr3b = (ushort*)alloc(48 * 256 * 2);

    // ---- prep: cvt_x + cvt_weights(frag-packed) + hist in one launch ----
    const int n4 = N * IN_DIM / 4;
    const int XB = (n4 + 255) / 256;
    const int WB = (32768 + 65536 + 48 * 256 + 255) / 256;
    const int HB = (E + 255) / 256;
    hipMemsetAsync(cnt, 0, (size_t)N * sizeof(int), stream);
    prep_kernel<<<XB + WB + HB, 256, 0, stream>>>(
        x, xb, n4, XB,
        Wl1, Wr1, Wl2, Wr2, Wl3, Wr3,
        Wl1b, Wr1b, Wl2b, Wr2b, Wl3b, Wr3b, WB,
        dst, cnt, E);

    // ---- CSR scan + fill ----
    const int SB = (N + SCAN_CHUNK - 1) / SCAN_CHUNK;  // 25
    scan_pass1<<<SB, 256, 0, stream>>>(cnt, bsum, N);
    scan_pass3<<<SB, 256, 0, stream>>>(cnt, bsum, rowptr, cursor, inv, N, E, SB);
    fill_kernel<<<HB, 256, 0, stream>>>(src, dst, cursor, srcs, E);

    const int gm = (N + 255) / 256;  // 196 row-tiles of 256 rows
    const int G = 4 * gm;            // 784: 4 col-blocks x row-tiles
    const int gg128 = (N + 15) / 16; // 4 nodes/wave, 16 nodes/block
    const int gg256 = (N + 7) / 8;   // 2 nodes/wave, 8 nodes/block
    const int gg = (N + 3) / 4;

    // ---- layer 1: K=128 -> 256, relu ----
    gather_mean_bf<IN_DIM><<<gg128, 256, 0, stream>>>(xb, rowptr, srcs, inv, M, N);
    sage_gemm_mfma<IN_DIM, true, true><<<G, 512, 0, stream>>>(
        M, xb, Wl1b, bl1, Wr1b, H1, N, HID_DIM, G);

    // ---- layer 2: K=256 -> 256, relu ----
    gather_mean_bf<HID_DIM><<<gg256, 256, 0, stream>>>(H1, rowptr, srcs, inv, M, N);
    sage_gemm_mfma<HID_DIM, true, true><<<G, 512, 0, stream>>>(
        M, H1, Wl2b, bl2, Wr2b, H2, N, HID_DIM, G);

    // ---- layer 3 (GEMM-first): P3 = H2@Wl3^T, S3 = H2@Wr3^T, then fused agg+lsm ----
    sage_gemm_pre<HID_DIM><<<(N + 63) / 64, 256, 0, stream>>>(
        H2, Wl3b, Wr3b, P3, S3, N, OUT_DIM);
    agg_bias_lsm<<<gg, 256, 0, stream>>>(P3, S3, bl3, rowptr, srcs, inv, out, N);
}

// Round 10
// 339.587 us; speedup vs baseline: 1.0172x; 1.0172x over previous
//
#include <hip/hip_runtime.h>
#include <hip/hip_bf16.h>

#define IN_DIM 128
#define HID_DIM 256
#define OUT_DIM 40
#define SCAN_CHUNK 2048

typedef __attribute__((ext_vector_type(8))) __bf16 bf16x8;
typedef __attribute__((ext_vector_type(4))) float f32x4;

__device__ inline ushort f2bf(float f) {
    uint u = __builtin_bit_cast(uint, f);
    u = (u + 0x7fff + ((u >> 16) & 1)) >> 16;
    return (ushort)u;
}
__device__ inline float bfl(uint u) { return __builtin_bit_cast(float, u << 16); }
__device__ inline float bfh(uint u) { return __builtin_bit_cast(float, u & 0xffff0000u); }

// async global->LDS, 16B per lane. dest base must be wave-uniform; HW adds lane*16.
// The GLOBAL source may be per-lane (m173) — used below for the A-swizzle staging.
__device__ inline void gload_lds16(const ushort* g, ushort* l) {
    __builtin_amdgcn_global_load_lds((const __attribute__((address_space(1))) void*)g,
                                     (__attribute__((address_space(3))) void*)l, 16, 0, 0);
}

// bijective XCD-chunked swizzle (m204)
__device__ inline int xcd_swizzle(int b, int G) {
    int q = G >> 3, r = G & 7;
    int xcd = b & 7, j = b >> 3;
    return (xcd < r ? xcd * (q + 1) : r * (q + 1) + (xcd - r) * q) + j;
}

// ---------------- fused prep: cvt_x + cvt_weights + hist (independent jobs) ----------------
__global__ __launch_bounds__(256) void prep_kernel(
    const float* __restrict__ x, ushort* __restrict__ xb, int n4, int XB,
    const float* __restrict__ Wl1, const float* __restrict__ Wr1,
    const float* __restrict__ Wl2, const float* __restrict__ Wr2,
    const float* __restrict__ Wl3, const float* __restrict__ Wr3,
    ushort* __restrict__ o1l, ushort* __restrict__ o1r,
    ushort* __restrict__ o2l, ushort* __restrict__ o2r,
    ushort* __restrict__ o3l, ushort* __restrict__ o3r, int WB,
    const int* __restrict__ dst, int* __restrict__ cnt, int E) {
    int b = blockIdx.x;
    if (b < XB) {
        int i = b * 256 + threadIdx.x;
        if (i < n4) {
            float4 v = ((const float4*)x)[i];
            uint2 o;
            o.x = (uint)f2bf(v.x) | ((uint)f2bf(v.y) << 16);
            o.y = (uint)f2bf(v.z) | ((uint)f2bf(v.w) << 16);
            ((uint2*)xb)[i] = o;
        }
        return;
    }
    b -= XB;
    if (b < WB) {
        int idx = b * 256 + threadIdx.x;
        if (idx < 32768) {
            // W1: K=128, NK=4. idx bits: j3 | ln4 | quad2 | kk2 | ct2 | cb2
            int j = idx & 7, ln = (idx >> 3) & 15, quad = (idx >> 7) & 3;
            int kk = (idx >> 9) & 3, ct = (idx >> 11) & 3, cb = idx >> 13;
            int o = cb * 64 + ct * 16 + ln;
            int k = kk * 32 + quad * 8 + j;
            o1l[idx] = f2bf(Wl1[o * 128 + k]);
            o1r[idx] = f2bf(Wr1[o * 128 + k]);
            return;
        }
        idx -= 32768;
        if (idx < 65536) {
            // W2: K=256, NK=8. idx bits: j3 | ln4 | quad2 | kk3 | ct2 | cb2
            int j = idx & 7, ln = (idx >> 3) & 15, quad = (idx >> 7) & 3;
            int kk = (idx >> 9) & 7, ct = (idx >> 12) & 3, cb = idx >> 14;
            int o = cb * 64 + ct * 16 + ln;
            int k = kk * 32 + quad * 8 + j;
            o2l[idx] = f2bf(Wl2[o * 256 + k]);
            o2r[idx] = f2bf(Wr2[o * 256 + k]);
            return;
        }
        idx -= 65536;
        if (idx < 48 * 256) {
            int row = idx >> 8;
            int col = idx & 255;
            ushort vl = 0, vr = 0;
            if (row < OUT_DIM) {
                vl = f2bf(Wl3[row * 256 + col]);
                vr = f2bf(Wr3[row * 256 + col]);
            }
            o3l[idx] = vl;
            o3r[idx] = vr;
        }
        return;
    }
    b -= WB;
    int e = b * 256 + threadIdx.x;
    if (e < E) atomicAdd(&cnt[dst[e]], 1);
}

// ---------------- CSR scan ----------------
__global__ __launch_bounds__(256) void scan_pass1(const int* __restrict__ cnt,
                                                  int* __restrict__ bsum, int N) {
    __shared__ int red[256];
    const int base = blockIdx.x * SCAN_CHUNK;
    int s = 0;
    for (int i = threadIdx.x; i < SCAN_CHUNK; i += 256) {
        int idx = base + i;
        if (idx < N) s += cnt[idx];
    }
    red[threadIdx.x] = s;
    __syncthreads();
    for (int o = 128; o > 0; o >>= 1) {
        if (threadIdx.x < o) red[threadIdx.x] += red[threadIdx.x + o];
        __syncthreads();
    }
    if (threadIdx.x == 0) bsum[blockIdx.x] = red[0];
}

__global__ __launch_bounds__(256) void scan_pass3(const int* __restrict__ cnt,
                                                  const int* __restrict__ bsum,
                                                  int* __restrict__ rowptr,
                                                  int* __restrict__ cursor,
                                                  float* __restrict__ inv,
                                                  int N, int E, int SB) {
    __shared__ int ls[256];
    __shared__ int boff;
    if (threadIdx.x == 0) {
        int r = 0;
        for (int i = 0; i < blockIdx.x; ++i) r += bsum[i];
        boff = r;
    }
    const int tbase = blockIdx.x * SCAN_CHUNK + threadIdx.x * 8;
    int c[8];
    int s = 0;
#pragma unroll
    for (int j = 0; j < 8; ++j) {
        int idx = tbase + j;
        c[j] = (idx < N) ? cnt[idx] : 0;
        s += c[j];
    }
    ls[threadIdx.x] = s;
    __syncthreads();
    for (int o = 1; o < 256; o <<= 1) {
        int u = (threadIdx.x >= o) ? ls[threadIdx.x - o] : 0;
        __syncthreads();
        ls[threadIdx.x] += u;
        __syncthreads();
    }
    int run = boff + ls[threadIdx.x] - s;
#pragma unroll
    for (int j = 0; j < 8; ++j) {
        int idx = tbase + j;
        if (idx < N) {
            rowptr[idx] = run;
            cursor[idx] = run;
            inv[idx] = 1.0f / fmaxf((float)c[j], 1.0f);
            run += c[j];
        }
    }
    if (blockIdx.x == 0 && threadIdx.x == 0) rowptr[N] = E;
}

__global__ __launch_bounds__(256) void fill_kernel(const int* __restrict__ src,
                                                   const int* __restrict__ dst,
                                                   int* __restrict__ cursor,
                                                   int* __restrict__ srcs, int E) {
    int e = blockIdx.x * 256 + threadIdx.x;
    if (e < E) {
        int pos = atomicAdd(&cursor[dst[e]], 1);
        srcs[pos] = src[e];
    }
}

// ---------------- gather mean (R18: multi-node/wave, 16B/lane uint4 loads) ----------------
template <int D>
__global__ __launch_bounds__(256) void gather_mean_bf(const ushort* __restrict__ feat,
                                                      const int* __restrict__ rowptr,
                                                      const int* __restrict__ srcs,
                                                      const float* __restrict__ inv,
                                                      ushort* __restrict__ out, int N) {
    constexpr int LPN = D / 8;       // lanes per node (16B per lane)
    constexpr int NPW = 64 / LPN;    // nodes per wave: 2 (D=256) or 4 (D=128)
    constexpr int NPB = 4 * NPW;     // nodes per block
    const int wave = threadIdx.x >> 6;
    const int lane = threadIdx.x & 63;
    const int sub = lane / LPN;
    const int sl = lane % LPN;
    const int n = blockIdx.x * NPB + wave * NPW + sub;
    const bool alive = n < N;
    const int beg = alive ? rowptr[n] : 0;
    const int end = alive ? rowptr[n + 1] : 0;
    const int col = sl * 8;

    float a0 = 0.f, a1 = 0.f, a2 = 0.f, a3 = 0.f;
    float a4 = 0.f, a5 = 0.f, a6 = 0.f, a7 = 0.f;
    int e = beg;
    for (; e + 3 < end; e += 4) {
        uint4 q[4];
#pragma unroll
        for (int j = 0; j < 4; ++j)
            q[j] = *(const uint4*)&feat[(long long)srcs[e + j] * D + col];
#pragma unroll
        for (int j = 0; j < 4; ++j) {
            a0 += bfl(q[j].x); a1 += bfh(q[j].x);
            a2 += bfl(q[j].y); a3 += bfh(q[j].y);
            a4 += bfl(q[j].z); a5 += bfh(q[j].z);
            a6 += bfl(q[j].w); a7 += bfh(q[j].w);
        }
    }
    for (; e < end; ++e) {
        uint4 q = *(const uint4*)&feat[(long long)srcs[e] * D + col];
        a0 += bfl(q.x); a1 += bfh(q.x);
        a2 += bfl(q.y); a3 += bfh(q.y);
        a4 += bfl(q.z); a5 += bfh(q.z);
        a6 += bfl(q.w); a7 += bfh(q.w);
    }
    if (alive) {
        const float sc = inv[n];
        uint4 o;
        o.x = (uint)f2bf(a0 * sc) | ((uint)f2bf(a1 * sc) << 16);
        o.y = (uint)f2bf(a2 * sc) | ((uint)f2bf(a3 * sc) << 16);
        o.z = (uint)f2bf(a4 * sc) | ((uint)f2bf(a5 * sc) << 16);
        o.w = (uint)f2bf(a6 * sc) | ((uint)f2bf(a7 * sc) << 16);
        *(uint4*)&out[(long long)n * D + col] = o;
    }
}

// ---------------- MFMA SAGE GEMM (R22: R21 + wave-row fix in the A ds_read) --------------
// Tile: 128 rows x 128 cols, 8 waves. Per phase: stage {W-half linear} + {A rows via
// INVERSE-SWIZZLED per-lane global source -> linear LDS dest} (rule #21c). ds_read applies
// the same XOR: byte ^= (row&7)<<4. MFMA loop reads LDS only. R21 bug: the A ds_read used
// row=ln, omitting the wave*16 tile-row offset -> every wave read rows 0-15. Fixed here.
template <int K, bool RELU, bool OUTBF>
__global__ __launch_bounds__(512, 4) void sage_gemm_mfma(const ushort* __restrict__ Amean,
                                                         const ushort* __restrict__ Aself,
                                                         const ushort* __restrict__ Wl,
                                                         const float* __restrict__ bias,
                                                         const ushort* __restrict__ Wr,
                                                         void* __restrict__ outv, int N, int O,
                                                         int G) {
    constexpr int NKK = K / 32;            // k-steps
    constexpr int RB = 2 * K;              // bytes per A row
    constexpr int LOGRB = (K == 256) ? 9 : 8;
    constexpr int TILE64 = 64 * K;         // ushorts per 64-col W group
    constexpr int AC = (128 * RB) / 1024;  // A 1KB chunks: 64 (K=256) / 32 (K=128)
    constexpr int WC = (2 * TILE64 * 2) / 1024;  // W 1KB chunks: 64 / 32
    __shared__ __align__(16) ushort As[128 * K];       // 64KB / 32KB
    __shared__ __align__(16) ushort Wsh[2 * TILE64];   // 64KB / 32KB

    const int tid = threadIdx.x;
    const int wave = tid >> 6;   // 0..7
    const int lane = tid & 63;
    const int ln = lane & 15;
    const int quad = lane >> 4;

    const int wid = xcd_swizzle(blockIdx.x, G);
    const int c2 = wid & 1;            // 128-col half (fast axis within XCD chunk)
    const int bm0 = (wid >> 1) * 128;  // row-block (128 rows: 8 waves x 16)

    f32x4 acc[8] = {};

#pragma unroll
    for (int p = 0; p < 2; ++p) {
        const ushort* __restrict__ A = (p ? Aself : Amean) + (size_t)bm0 * K;
        const ushort* __restrict__ Wg = (p ? Wr : Wl) + (size_t)c2 * 2 * TILE64;

        if (p) __syncthreads();  // all waves done reading phase-0 LDS

        // ---- stage W: linear (frag-packed global => frag-order LDS) ----
#pragma unroll
        for (int c = wave; c < WC; c += 8)
            gload_lds16(Wg + c * 512 + lane * 8, &Wsh[c * 512]);

        // ---- stage A: linear LDS dest, inverse-swizzled per-lane global src ----
#pragma unroll
        for (int c = wave; c < AC; c += 8) {
            int q = c * 1024 + lane * 16;           // linear LDS byte pos (this lane)
            int row = q >> LOGRB;
            int inrow = q & (RB - 1);
            int srcb = (row << LOGRB) + (inrow ^ ((row & 7) << 4));
            gload_lds16(A + (srcb >> 1), &As[c * 512]);
        }

        __syncthreads();  // drains vmcnt(0): both stages complete

        // ---- MFMA loop: LDS only ----
#pragma unroll
        for (int kk = 0; kk < NKK; ++kk) {
            // tile row = wave*16 + ln (R21 bug: was just ln)
            bf16x8 a = *(const bf16x8*)&As[((wave * 16 + ln) * RB +
                                            ((kk * 64 + quad * 16) ^ ((ln & 7) << 4))) >> 1];
#pragma unroll
            for (int ct = 0; ct < 8; ++ct) {
                bf16x8 b = *(const bf16x8*)&Wsh[(ct >> 2) * TILE64 + (((ct & 3) * NKK + kk) * 64 + lane) * 8];
                acc[ct] = __builtin_amdgcn_mfma_f32_16x16x32_bf16(a, b, acc[ct], 0, 0, 0);
            }
        }
    }

    // ---- epilogue ----
    {
        int rbase = bm0 + wave * 16 + quad * 4;
#pragma unroll
        for (int ct = 0; ct < 8; ++ct) {
            int col = c2 * 128 + ct * 16 + ln;
            if (col >= O) continue;
            float bv = bias[col];
#pragma unroll
            for (int r = 0; r < 4; ++r) {
                int row = rbase + r;
                if (row >= N) continue;
                float v = acc[ct][r] + bv;
                if (RELU) v = fmaxf(v, 0.f);
                if (OUTBF)
                    ((ushort*)outv)[(long long)row * O + col] = f2bf(v);
                else
                    ((float*)outv)[(long long)row * O + col] = v;
            }
        }
    }
}

// ---------------- layer-3 pre-aggregation GEMM: P = A@Wl^T (bf16), S = A@Wr^T (fp32) ----------------
template <int K>
__global__ __launch_bounds__(256, 3) void sage_gemm_pre(const ushort* __restrict__ A0,
                                                        const ushort* __restrict__ Wl,
                                                        const ushort* __restrict__ Wr,
                                                        ushort* __restrict__ P,
                                                        float* __restrict__ S, int N, int O) {
    constexpr int KP = 2 * K + 8;
    constexpr int NK = K / 32;  // 8
    __shared__ __align__(16) ushort Ws[48 * KP];  // 49 KB

    const int tid = threadIdx.x;
    const int wave = tid >> 6;
    const int lane = tid & 63;
    const int ln = lane & 15;
    const int quad = lane >> 4;
    const int bm0 = blockIdx.x * 64;

    const int arow = min(bm0 + wave * 16 + ln, N - 1);

#pragma unroll
    for (int i = tid; i < 48 * (K / 8); i += 256) {
        int row = i / (K / 8);
        int c8 = (i % (K / 8)) * 8;
        *(ulonglong2*)&Ws[row * KP + c8] =
            *(const ulonglong2*)&Wl[(long long)row * K + c8];
        *(ulonglong2*)&Ws[row * KP + K + c8] =
            *(const ulonglong2*)&Wr[(long long)row * K + c8];
    }
    __syncthreads();

#pragma unroll
    for (int phase = 0; phase < 2; ++phase) {
        f32x4 acc[3] = {};
#pragma unroll
        for (int kk = 0; kk < NK; ++kk) {
            bf16x8 a = *(const bf16x8*)&A0[(long long)arow * K + kk * 32 + quad * 8];
#pragma unroll
            for (int ct = 0; ct < 3; ++ct) {
                bf16x8 b = *(const bf16x8*)&Ws[(ct * 16 + ln) * KP + phase * K + kk * 32 + quad * 8];
                acc[ct] = __builtin_amdgcn_mfma_f32_16x16x32_bf16(a, b, acc[ct], 0, 0, 0);
            }
        }
        int rbase = bm0 + wave * 16 + quad * 4;
#pragma unroll
        for (int ct = 0; ct < 3; ++ct) {
            int col = ct * 16 + ln;
            if (col >= O) continue;
#pragma unroll
            for (int r = 0; r < 4; ++r) {
                int row = rbase + r;
                if (row >= N) continue;
                if (phase == 0)
                    P[(long long)row * O + col] = f2bf(acc[ct][r]);
                else
                    S[(long long)row * O + col] = acc[ct][r];
            }
        }
    }
}

// ---------------- fused mean-agg(D=40) + self + bias + log_softmax ----------------
__global__ __launch_bounds__(256) void agg_bias_lsm(const ushort* __restrict__ P,
                                                    const float* __restrict__ S,
                                                    const float* __restrict__ bias,
                                                    const int* __restrict__ rowptr,
                                                    const int* __restrict__ srcs,
                                                    const float* __restrict__ inv,
                                                    float* __restrict__ out, int N) {
    const int wave = threadIdx.x >> 6;
    const int lane = threadIdx.x & 63;
    const int n = blockIdx.x * 4 + wave;
    if (n >= N) return;
    const int beg = rowptr[n];
    const int end = rowptr[n + 1];
    const bool act = lane < OUT_DIM;
    const int cidx = act ? lane : 0;

    float acc = 0.f;
    int e = beg;
    for (; e + 3 < end; e += 4) {
        int s0 = srcs[e], s1 = srcs[e + 1], s2 = srcs[e + 2], s3 = srcs[e + 3];
        float v0 = __builtin_bit_cast(float, (uint)P[(long long)s0 * OUT_DIM + cidx] << 16);
        float v1 = __builtin_bit_cast(float, (uint)P[(long long)s1 * OUT_DIM + cidx] << 16);
        float v2 = __builtin_bit_cast(float, (uint)P[(long long)s2 * OUT_DIM + cidx] << 16);
        float v3 = __builtin_bit_cast(float, (uint)P[(long long)s3 * OUT_DIM + cidx] << 16);
        acc += (v0 + v1) + (v2 + v3);
    }
    for (; e < end; ++e)
        acc += __builtin_bit_cast(float, (uint)P[(long long)srcs[e] * OUT_DIM + cidx] << 16);

    float v = act ? (acc * inv[n] + S[(long long)n * OUT_DIM + lane] + bias[lane]) : -INFINITY;
    float m = v;
#pragma unroll
    for (int o = 32; o > 0; o >>= 1) m = fmaxf(m, __shfl_xor(m, o, 64));
    float ex = act ? expf(v - m) : 0.f;
    float sm = ex;
#pragma unroll
    for (int o = 32; o > 0; o >>= 1) sm += __shfl_xor(sm, o, 64);
    float ls = logf(sm);
    if (act) out[(long long)n * OUT_DIM + lane] = v - m - ls;
}

extern "C" void kernel_launch(void* const* d_in, const int* in_sizes, int n_in,
                              void* d_out, int out_size, void* d_ws, size_t ws_size,
                              hipStream_t stream) {
    const float* x   = (const float*)d_in[0];
    const int*   ei  = (const int*)d_in[1];
    const float* Wl1 = (const float*)d_in[2];
    const float* bl1 = (const float*)d_in[3];
    const float* Wr1 = (const float*)d_in[4];
    const float* Wl2 = (const float*)d_in[5];
    const float* bl2 = (const float*)d_in[6];
    const float* Wr2 = (const float*)d_in[7];
    const float* Wl3 = (const float*)d_in[8];
    const float* bl3 = (const float*)d_in[9];
    const float* Wr3 = (const float*)d_in[10];
    float* out = (float*)d_out;

    const int N = in_sizes[0] / IN_DIM;  // 50000
    const int E = in_sizes[1] / 2;       // 600000
    const int* src = ei;
    const int* dst = ei + E;

    // ---- workspace layout ----
    char* w = (char*)d_ws;
    size_t off = 0;
    auto alloc = [&](size_t bytes) {
        void* p = w + off;
        off = (off + bytes + 255) & ~(size_t)255;
        return p;
    };
    ushort* xb   = (ushort*)alloc((size_t)N * IN_DIM * 2);
    ushort* M    = (ushort*)alloc((size_t)N * HID_DIM * 2);
    ushort* H1   = (ushort*)alloc((size_t)N * HID_DIM * 2);
    ushort* H2   = (ushort*)alloc((size_t)N * HID_DIM * 2);
    ushort* P3   = (ushort*)alloc((size_t)N * OUT_DIM * 2);
    float*  S3   = (float*)alloc((size_t)N * OUT_DIM * 4);
    float*  inv  = (float*)alloc((size_t)N * 4);
    int*    cnt  = (int*)alloc((size_t)N * 4);
    int*    rowptr = (int*)alloc((size_t)(N + 1) * 4);
    int*    cursor = (int*)alloc((size_t)N * 4);
    int*    srcs = (int*)alloc((size_t)E * 4);
    int*    bsum = (int*)alloc(256 * 4);
    ushort* Wl1b = (ushort*)alloc(256 * 128 * 2);
    ushort* Wr1b = (ushort*)alloc(256 * 128 * 2);
    ushort* Wl2b = (ushort*)alloc(256 * 256 * 2);
    ushort* Wr2b = (ushort*)alloc(256 * 256 * 2);
    ushort* Wl3b = (ushort*)alloc(48 * 256 * 2);
    ushort* Wr3b = (ushort*)alloc(48 * 256 * 2);
    (void)alloc(64 * 1024);  // guard slack: A-stage may read up to 48 rows past N

    // ---- prep: cvt_x + cvt_weights(frag-packed) + hist in one launch ----
    const int n4 = N * IN_DIM / 4;
    const int XB = (n4 + 255) / 256;
    const int WB = (32768 + 65536 + 48 * 256 + 255) / 256;
    const int HB = (E + 255) / 256;
    hipMemsetAsync(cnt, 0, (size_t)N * sizeof(int), stream);
    prep_kernel<<<XB + WB + HB, 256, 0, stream>>>(
        x, xb, n4, XB,
        Wl1, Wr1, Wl2, Wr2, Wl3, Wr3,
        Wl1b, Wr1b, Wl2b, Wr2b, Wl3b, Wr3b, WB,
        dst, cnt, E);

    // ---- CSR scan + fill ----
    const int SB = (N + SCAN_CHUNK - 1) / SCAN_CHUNK;  // 25
    scan_pass1<<<SB, 256, 0, stream>>>(cnt, bsum, N);
    scan_pass3<<<SB, 256, 0, stream>>>(cnt, bsum, rowptr, cursor, inv, N, E, SB);
    fill_kernel<<<HB, 256, 0, stream>>>(src, dst, cursor, srcs, E);

    const int gmr = (N + 127) / 128;  // 391 row-tiles of 128 rows
    const int G = 2 * gmr;            // 782: 2 col-halves x row-tiles
    const int gg128 = (N + 15) / 16;  // 4 nodes/wave, 16 nodes/block
    const int gg256 = (N + 7) / 8;    // 2 nodes/wave, 8 nodes/block
    const int gg = (N + 3) / 4;

    // ---- layer 1: K=128 -> 256, relu ----
    gather_mean_bf<IN_DIM><<<gg128, 256, 0, stream>>>(xb, rowptr, srcs, inv, M, N);
    sage_gemm_mfma<IN_DIM, true, true><<<G, 512, 0, stream>>>(
        M, xb, Wl1b, bl1, Wr1b, H1, N, HID_DIM, G);

    // ---- layer 2: K=256 -> 256, relu ----
    gather_mean_bf<HID_DIM><<<gg256, 256, 0, stream>>>(H1, rowptr, srcs, inv, M, N);
    sage_gemm_mfma<HID_DIM, true, true><<<G, 512, 0, stream>>>(
        M, H1, Wl2b, bl2, Wr2b, H2, N, HID_DIM, G);

    // ---- layer 3 (GEMM-first): P3 = H2@Wl3^T, S3 = H2@Wr3^T, then fused agg+lsm ----
    sage_gemm_pre<HID_DIM><<<(N + 63) / 64, 256, 0, stream>>>(
        H2, Wl3b, Wr3b, P3, S3, N, OUT_DIM);
    agg_bias_lsm<<<gg, 256, 0, stream>>>(P3, S3, bl3, rowptr, srcs, inv, out, N);
}

// Round 11
// 338.608 us; speedup vs baseline: 1.0201x; 1.0029x over previous
//
#include <hip/hip_runtime.h>
#include <hip/hip_bf16.h>

#define IN_DIM 128
#define HID_DIM 256
#define OUT_DIM 40
#define SCAN_CHUNK 2048

typedef __attribute__((ext_vector_type(8))) __bf16 bf16x8;
typedef __attribute__((ext_vector_type(4))) float f32x4;

__device__ inline ushort f2bf(float f) {
    uint u = __builtin_bit_cast(uint, f);
    u = (u + 0x7fff + ((u >> 16) & 1)) >> 16;
    return (ushort)u;
}
__device__ inline float bfl(uint u) { return __builtin_bit_cast(float, u << 16); }
__device__ inline float bfh(uint u) { return __builtin_bit_cast(float, u & 0xffff0000u); }

// async global->LDS, 16B per lane. dest base must be wave-uniform; HW adds lane*16.
// The GLOBAL source may be per-lane (m173) — used for the A-swizzle staging.
__device__ inline void gload_lds16(const ushort* g, ushort* l) {
    __builtin_amdgcn_global_load_lds((const __attribute__((address_space(1))) void*)g,
                                     (__attribute__((address_space(3))) void*)l, 16, 0, 0);
}

// bijective XCD-chunked swizzle (m204)
__device__ inline int xcd_swizzle(int b, int G) {
    int q = G >> 3, r = G & 7;
    int xcd = b & 7, j = b >> 3;
    return (xcd < r ? xcd * (q + 1) : r * (q + 1) + (xcd - r) * q) + j;
}

// ---------------- fused prep: cvt_x + cvt_weights + hist (independent jobs) ----------------
__global__ __launch_bounds__(256) void prep_kernel(
    const float* __restrict__ x, ushort* __restrict__ xb, int n4, int XB,
    const float* __restrict__ Wl1, const float* __restrict__ Wr1,
    const float* __restrict__ Wl2, const float* __restrict__ Wr2,
    const float* __restrict__ Wl3, const float* __restrict__ Wr3,
    ushort* __restrict__ o1l, ushort* __restrict__ o1r,
    ushort* __restrict__ o2l, ushort* __restrict__ o2r,
    ushort* __restrict__ o3l, ushort* __restrict__ o3r, int WB,
    const int* __restrict__ dst, int* __restrict__ cnt, int E) {
    int b = blockIdx.x;
    if (b < XB) {
        int i = b * 256 + threadIdx.x;
        if (i < n4) {
            float4 v = ((const float4*)x)[i];
            uint2 o;
            o.x = (uint)f2bf(v.x) | ((uint)f2bf(v.y) << 16);
            o.y = (uint)f2bf(v.z) | ((uint)f2bf(v.w) << 16);
            ((uint2*)xb)[i] = o;
        }
        return;
    }
    b -= XB;
    if (b < WB) {
        int idx = b * 256 + threadIdx.x;
        if (idx < 32768) {
            // W1: K=128, NK=4. idx bits: j3 | ln4 | quad2 | kk2 | ct2 | cb2
            int j = idx & 7, ln = (idx >> 3) & 15, quad = (idx >> 7) & 3;
            int kk = (idx >> 9) & 3, ct = (idx >> 11) & 3, cb = idx >> 13;
            int o = cb * 64 + ct * 16 + ln;
            int k = kk * 32 + quad * 8 + j;
            o1l[idx] = f2bf(Wl1[o * 128 + k]);
            o1r[idx] = f2bf(Wr1[o * 128 + k]);
            return;
        }
        idx -= 32768;
        if (idx < 65536) {
            // W2: K=256, NK=8. idx bits: j3 | ln4 | quad2 | kk3 | ct2 | cb2
            int j = idx & 7, ln = (idx >> 3) & 15, quad = (idx >> 7) & 3;
            int kk = (idx >> 9) & 7, ct = (idx >> 12) & 3, cb = idx >> 14;
            int o = cb * 64 + ct * 16 + ln;
            int k = kk * 32 + quad * 8 + j;
            o2l[idx] = f2bf(Wl2[o * 256 + k]);
            o2r[idx] = f2bf(Wr2[o * 256 + k]);
            return;
        }
        idx -= 65536;
        if (idx < 48 * 256) {
            int row = idx >> 8;
            int col = idx & 255;
            ushort vl = 0, vr = 0;
            if (row < OUT_DIM) {
                vl = f2bf(Wl3[row * 256 + col]);
                vr = f2bf(Wr3[row * 256 + col]);
            }
            o3l[idx] = vl;
            o3r[idx] = vr;
        }
        return;
    }
    b -= WB;
    int e = b * 256 + threadIdx.x;
    if (e < E) atomicAdd(&cnt[dst[e]], 1);
}

// ---------------- CSR scan ----------------
__global__ __launch_bounds__(256) void scan_pass1(const int* __restrict__ cnt,
                                                  int* __restrict__ bsum, int N) {
    __shared__ int red[256];
    const int base = blockIdx.x * SCAN_CHUNK;
    int s = 0;
    for (int i = threadIdx.x; i < SCAN_CHUNK; i += 256) {
        int idx = base + i;
        if (idx < N) s += cnt[idx];
    }
    red[threadIdx.x] = s;
    __syncthreads();
    for (int o = 128; o > 0; o >>= 1) {
        if (threadIdx.x < o) red[threadIdx.x] += red[threadIdx.x + o];
        __syncthreads();
    }
    if (threadIdx.x == 0) bsum[blockIdx.x] = red[0];
}

__global__ __launch_bounds__(256) void scan_pass3(const int* __restrict__ cnt,
                                                  const int* __restrict__ bsum,
                                                  int* __restrict__ rowptr,
                                                  int* __restrict__ cursor,
                                                  float* __restrict__ inv,
                                                  int N, int E, int SB) {
    __shared__ int ls[256];
    __shared__ int boff;
    if (threadIdx.x == 0) {
        int r = 0;
        for (int i = 0; i < blockIdx.x; ++i) r += bsum[i];
        boff = r;
    }
    const int tbase = blockIdx.x * SCAN_CHUNK + threadIdx.x * 8;
    int c[8];
    int s = 0;
#pragma unroll
    for (int j = 0; j < 8; ++j) {
        int idx = tbase + j;
        c[j] = (idx < N) ? cnt[idx] : 0;
        s += c[j];
    }
    ls[threadIdx.x] = s;
    __syncthreads();
    for (int o = 1; o < 256; o <<= 1) {
        int u = (threadIdx.x >= o) ? ls[threadIdx.x - o] : 0;
        __syncthreads();
        ls[threadIdx.x] += u;
        __syncthreads();
    }
    int run = boff + ls[threadIdx.x] - s;
#pragma unroll
    for (int j = 0; j < 8; ++j) {
        int idx = tbase + j;
        if (idx < N) {
            rowptr[idx] = run;
            cursor[idx] = run;
            inv[idx] = 1.0f / fmaxf((float)c[j], 1.0f);
            run += c[j];
        }
    }
    if (blockIdx.x == 0 && threadIdx.x == 0) rowptr[N] = E;
}

__global__ __launch_bounds__(256) void fill_kernel(const int* __restrict__ src,
                                                   const int* __restrict__ dst,
                                                   int* __restrict__ cursor,
                                                   int* __restrict__ srcs, int E) {
    int e = blockIdx.x * 256 + threadIdx.x;
    if (e < E) {
        int pos = atomicAdd(&cursor[dst[e]], 1);
        srcs[pos] = src[e];
    }
}

// ---------------- gather mean (R18: multi-node/wave, 16B/lane uint4 loads) ----------------
template <int D>
__global__ __launch_bounds__(256) void gather_mean_bf(const ushort* __restrict__ feat,
                                                      const int* __restrict__ rowptr,
                                                      const int* __restrict__ srcs,
                                                      const float* __restrict__ inv,
                                                      ushort* __restrict__ out, int N) {
    constexpr int LPN = D / 8;       // lanes per node (16B per lane)
    constexpr int NPW = 64 / LPN;    // nodes per wave: 2 (D=256) or 4 (D=128)
    constexpr int NPB = 4 * NPW;     // nodes per block
    const int wave = threadIdx.x >> 6;
    const int lane = threadIdx.x & 63;
    const int sub = lane / LPN;
    const int sl = lane % LPN;
    const int n = blockIdx.x * NPB + wave * NPW + sub;
    const bool alive = n < N;
    const int beg = alive ? rowptr[n] : 0;
    const int end = alive ? rowptr[n + 1] : 0;
    const int col = sl * 8;

    float a0 = 0.f, a1 = 0.f, a2 = 0.f, a3 = 0.f;
    float a4 = 0.f, a5 = 0.f, a6 = 0.f, a7 = 0.f;
    int e = beg;
    for (; e + 3 < end; e += 4) {
        uint4 q[4];
#pragma unroll
        for (int j = 0; j < 4; ++j)
            q[j] = *(const uint4*)&feat[(long long)srcs[e + j] * D + col];
#pragma unroll
        for (int j = 0; j < 4; ++j) {
            a0 += bfl(q[j].x); a1 += bfh(q[j].x);
            a2 += bfl(q[j].y); a3 += bfh(q[j].y);
            a4 += bfl(q[j].z); a5 += bfh(q[j].z);
            a6 += bfl(q[j].w); a7 += bfh(q[j].w);
        }
    }
    for (; e < end; ++e) {
        uint4 q = *(const uint4*)&feat[(long long)srcs[e] * D + col];
        a0 += bfl(q.x); a1 += bfh(q.x);
        a2 += bfl(q.y); a3 += bfh(q.y);
        a4 += bfl(q.z); a5 += bfh(q.z);
        a6 += bfl(q.w); a7 += bfh(q.w);
    }
    if (alive) {
        const float sc = inv[n];
        uint4 o;
        o.x = (uint)f2bf(a0 * sc) | ((uint)f2bf(a1 * sc) << 16);
        o.y = (uint)f2bf(a2 * sc) | ((uint)f2bf(a3 * sc) << 16);
        o.z = (uint)f2bf(a4 * sc) | ((uint)f2bf(a5 * sc) << 16);
        o.w = (uint)f2bf(a6 * sc) | ((uint)f2bf(a7 * sc) << 16);
        *(uint4*)&out[(long long)n * D + col] = o;
    }
}

// ---------------- LAYER-1 GEMM (R22 LDS-A structure: measured win at K=128, 64KB LDS) ----
// 128 rows x 128 cols, 8 waves. Per phase: stage {W-half linear} + {A via inverse-swizzled
// per-lane global src -> linear LDS dest}; ds_read applies byte ^= (row&7)<<4.
template <int K, bool RELU, bool OUTBF>
__global__ __launch_bounds__(512, 4) void sage_gemm_ldsA(const ushort* __restrict__ Amean,
                                                         const ushort* __restrict__ Aself,
                                                         const ushort* __restrict__ Wl,
                                                         const float* __restrict__ bias,
                                                         const ushort* __restrict__ Wr,
                                                         void* __restrict__ outv, int N, int O,
                                                         int G) {
    constexpr int NKK = K / 32;            // k-steps
    constexpr int RB = 2 * K;              // bytes per A row
    constexpr int LOGRB = (K == 256) ? 9 : 8;
    constexpr int TILE64 = 64 * K;         // ushorts per 64-col W group
    constexpr int AC = (128 * RB) / 1024;  // A 1KB chunks
    constexpr int WC = (2 * TILE64 * 2) / 1024;  // W 1KB chunks
    __shared__ __align__(16) ushort As[128 * K];
    __shared__ __align__(16) ushort Wsh[2 * TILE64];

    const int tid = threadIdx.x;
    const int wave = tid >> 6;   // 0..7
    const int lane = tid & 63;
    const int ln = lane & 15;
    const int quad = lane >> 4;

    const int wid = xcd_swizzle(blockIdx.x, G);
    const int c2 = wid & 1;            // 128-col half
    const int bm0 = (wid >> 1) * 128;  // row-block (128 rows: 8 waves x 16)

    f32x4 acc[8] = {};

#pragma unroll
    for (int p = 0; p < 2; ++p) {
        const ushort* __restrict__ A = (p ? Aself : Amean) + (size_t)bm0 * K;
        const ushort* __restrict__ Wg = (p ? Wr : Wl) + (size_t)c2 * 2 * TILE64;

        if (p) __syncthreads();  // all waves done reading phase-0 LDS

#pragma unroll
        for (int c = wave; c < WC; c += 8)
            gload_lds16(Wg + c * 512 + lane * 8, &Wsh[c * 512]);

#pragma unroll
        for (int c = wave; c < AC; c += 8) {
            int q = c * 1024 + lane * 16;           // linear LDS byte pos (this lane)
            int row = q >> LOGRB;
            int inrow = q & (RB - 1);
            int srcb = (row << LOGRB) + (inrow ^ ((row & 7) << 4));
            gload_lds16(A + (srcb >> 1), &As[c * 512]);
        }

        __syncthreads();  // drains vmcnt(0): both stages complete

#pragma unroll
        for (int kk = 0; kk < NKK; ++kk) {
            bf16x8 a = *(const bf16x8*)&As[((wave * 16 + ln) * RB +
                                            ((kk * 64 + quad * 16) ^ ((ln & 7) << 4))) >> 1];
#pragma unroll
            for (int ct = 0; ct < 8; ++ct) {
                bf16x8 b = *(const bf16x8*)&Wsh[(ct >> 2) * TILE64 + (((ct & 3) * NKK + kk) * 64 + lane) * 8];
                acc[ct] = __builtin_amdgcn_mfma_f32_16x16x32_bf16(a, b, acc[ct], 0, 0, 0);
            }
        }
    }

    {
        int rbase = bm0 + wave * 16 + quad * 4;
#pragma unroll
        for (int ct = 0; ct < 8; ++ct) {
            int col = c2 * 128 + ct * 16 + ln;
            if (col >= O) continue;
            float bv = bias[col];
#pragma unroll
            for (int r = 0; r < 4; ++r) {
                int row = rbase + r;
                if (row >= N) continue;
                float v = acc[ct][r] + bv;
                if (RELU) v = fmaxf(v, 0.f);
                if (OUTBF)
                    ((ushort*)outv)[(long long)row * O + col] = f2bf(v);
                else
                    ((float*)outv)[(long long)row * O + col] = v;
            }
        }
    }
}

// ---------------- LAYER-2 GEMM (R17 structure: measured best 46.2us at K=256) ------------
// 256 rows x 64 cols, 8 waves, stage BOTH frag-packed W tiles once, ONE barrier,
// phase-1 A reloads issued under phase-0 MFMAs.
template <int K, bool RELU, bool OUTBF>
__global__ __launch_bounds__(512, 4) void sage_gemm_r17(const ushort* __restrict__ Amean,
                                                        const ushort* __restrict__ Aself,
                                                        const ushort* __restrict__ Wl,
                                                        const float* __restrict__ bias,
                                                        const ushort* __restrict__ Wr,
                                                        void* __restrict__ outv, int N, int O,
                                                        int G) {
    constexpr int NK = K / 32;            // k-steps per phase
    constexpr int TILE = 64 * K;          // ushorts per (cb, matrix) W tile
    constexpr int CHUNKS = TILE / 512;    // 1KB chunks
    __shared__ __align__(16) ushort Ws[2 * TILE];  // K=256: 64KB

    const int tid = threadIdx.x;
    const int wave = tid >> 6;   // 0..7
    const int lane = tid & 63;
    const int ln = lane & 15;
    const int quad = lane >> 4;

    const int wid = xcd_swizzle(blockIdx.x, G);
    const int cb = wid & 3;            // col-block: fast axis within an XCD chunk
    const int bm0 = (wid >> 2) * 256;  // row-block (256 rows: 8 waves x 32)

    {
        const ushort* gl = Wl + (size_t)cb * TILE;
        const ushort* gr = Wr + (size_t)cb * TILE;
#pragma unroll
        for (int c = wave; c < CHUNKS; c += 8) {
            gload_lds16(gl + c * 512 + lane * 8, &Ws[c * 512]);
            gload_lds16(gr + c * 512 + lane * 8, &Ws[TILE + c * 512]);
        }
    }

    int arow[2];
#pragma unroll
    for (int rt = 0; rt < 2; ++rt) {
        int r = bm0 + wave * 32 + rt * 16 + ln;
        arow[rt] = min(r, N - 1);
    }

    bf16x8 areg[NK][2];
#pragma unroll
    for (int kk = 0; kk < NK; ++kk)
#pragma unroll
        for (int rt = 0; rt < 2; ++rt)
            areg[kk][rt] = *(const bf16x8*)&Amean[(long long)arow[rt] * K + kk * 32 + quad * 8];

    f32x4 acc[2][4] = {};
    __syncthreads();  // ONE barrier: drains gll + phase-0 areg

#pragma unroll
    for (int kk = 0; kk < NK; ++kk) {
#pragma unroll
        for (int ct = 0; ct < 4; ++ct) {
            bf16x8 b = *(const bf16x8*)&Ws[((ct * NK + kk) * 64 + lane) * 8];
#pragma unroll
            for (int rt = 0; rt < 2; ++rt)
                acc[rt][ct] = __builtin_amdgcn_mfma_f32_16x16x32_bf16(areg[kk][rt], b, acc[rt][ct], 0, 0, 0);
        }
#pragma unroll
        for (int rt = 0; rt < 2; ++rt)
            areg[kk][rt] = *(const bf16x8*)&Aself[(long long)arow[rt] * K + kk * 32 + quad * 8];
    }

#pragma unroll
    for (int kk = 0; kk < NK; ++kk) {
#pragma unroll
        for (int ct = 0; ct < 4; ++ct) {
            bf16x8 b = *(const bf16x8*)&Ws[TILE + ((ct * NK + kk) * 64 + lane) * 8];
#pragma unroll
            for (int rt = 0; rt < 2; ++rt)
                acc[rt][ct] = __builtin_amdgcn_mfma_f32_16x16x32_bf16(areg[kk][rt], b, acc[rt][ct], 0, 0, 0);
        }
    }

#pragma unroll
    for (int rt = 0; rt < 2; ++rt) {
        int rbase = bm0 + wave * 32 + rt * 16 + quad * 4;
#pragma unroll
        for (int ct = 0; ct < 4; ++ct) {
            int col = cb * 64 + ct * 16 + ln;
            if (col >= O) continue;
            float bv = bias[col];
#pragma unroll
            for (int r = 0; r < 4; ++r) {
                int row = rbase + r;
                if (row >= N) continue;
                float v = acc[rt][ct][r] + bv;
                if (RELU) v = fmaxf(v, 0.f);
                if (OUTBF)
                    ((ushort*)outv)[(long long)row * O + col] = f2bf(v);
                else
                    ((float*)outv)[(long long)row * O + col] = v;
            }
        }
    }
}

// ---------------- layer-3 pre-aggregation GEMM: P = A@Wl^T (bf16), S = A@Wr^T (fp32) ----------------
template <int K>
__global__ __launch_bounds__(256, 3) void sage_gemm_pre(const ushort* __restrict__ A0,
                                                        const ushort* __restrict__ Wl,
                                                        const ushort* __restrict__ Wr,
                                                        ushort* __restrict__ P,
                                                        float* __restrict__ S, int N, int O) {
    constexpr int KP = 2 * K + 8;
    constexpr int NK = K / 32;  // 8
    __shared__ __align__(16) ushort Ws[48 * KP];  // 49 KB

    const int tid = threadIdx.x;
    const int wave = tid >> 6;
    const int lane = tid & 63;
    const int ln = lane & 15;
    const int quad = lane >> 4;
    const int bm0 = blockIdx.x * 64;

    const int arow = min(bm0 + wave * 16 + ln, N - 1);

#pragma unroll
    for (int i = tid; i < 48 * (K / 8); i += 256) {
        int row = i / (K / 8);
        int c8 = (i % (K / 8)) * 8;
        *(ulonglong2*)&Ws[row * KP + c8] =
            *(const ulonglong2*)&Wl[(long long)row * K + c8];
        *(ulonglong2*)&Ws[row * KP + K + c8] =
            *(const ulonglong2*)&Wr[(long long)row * K + c8];
    }
    __syncthreads();

#pragma unroll
    for (int phase = 0; phase < 2; ++phase) {
        f32x4 acc[3] = {};
#pragma unroll
        for (int kk = 0; kk < NK; ++kk) {
            bf16x8 a = *(const bf16x8*)&A0[(long long)arow * K + kk * 32 + quad * 8];
#pragma unroll
            for (int ct = 0; ct < 3; ++ct) {
                bf16x8 b = *(const bf16x8*)&Ws[(ct * 16 + ln) * KP + phase * K + kk * 32 + quad * 8];
                acc[ct] = __builtin_amdgcn_mfma_f32_16x16x32_bf16(a, b, acc[ct], 0, 0, 0);
            }
        }
        int rbase = bm0 + wave * 16 + quad * 4;
#pragma unroll
        for (int ct = 0; ct < 3; ++ct) {
            int col = ct * 16 + ln;
            if (col >= O) continue;
#pragma unroll
            for (int r = 0; r < 4; ++r) {
                int row = rbase + r;
                if (row >= N) continue;
                if (phase == 0)
                    P[(long long)row * O + col] = f2bf(acc[ct][r]);
                else
                    S[(long long)row * O + col] = acc[ct][r];
            }
        }
    }
}

// ---------------- fused mean-agg(D=40) + self + bias + log_softmax ----------------
__global__ __launch_bounds__(256) void agg_bias_lsm(const ushort* __restrict__ P,
                                                    const float* __restrict__ S,
                                                    const float* __restrict__ bias,
                                                    const int* __restrict__ rowptr,
                                                    const int* __restrict__ srcs,
                                                    const float* __restrict__ inv,
                                                    float* __restrict__ out, int N) {
    const int wave = threadIdx.x >> 6;
    const int lane = threadIdx.x & 63;
    const int n = blockIdx.x * 4 + wave;
    if (n >= N) return;
    const int beg = rowptr[n];
    const int end = rowptr[n + 1];
    const bool act = lane < OUT_DIM;
    const int cidx = act ? lane : 0;

    float acc = 0.f;
    int e = beg;
    for (; e + 3 < end; e += 4) {
        int s0 = srcs[e], s1 = srcs[e + 1], s2 = srcs[e + 2], s3 = srcs[e + 3];
        float v0 = __builtin_bit_cast(float, (uint)P[(long long)s0 * OUT_DIM + cidx] << 16);
        float v1 = __builtin_bit_cast(float, (uint)P[(long long)s1 * OUT_DIM + cidx] << 16);
        float v2 = __builtin_bit_cast(float, (uint)P[(long long)s2 * OUT_DIM + cidx] << 16);
        float v3 = __builtin_bit_cast(float, (uint)P[(long long)s3 * OUT_DIM + cidx] << 16);
        acc += (v0 + v1) + (v2 + v3);
    }
    for (; e < end; ++e)
        acc += __builtin_bit_cast(float, (uint)P[(long long)srcs[e] * OUT_DIM + cidx] << 16);

    float v = act ? (acc * inv[n] + S[(long long)n * OUT_DIM + lane] + bias[lane]) : -INFINITY;
    float m = v;
#pragma unroll
    for (int o = 32; o > 0; o >>= 1) m = fmaxf(m, __shfl_xor(m, o, 64));
    float ex = act ? expf(v - m) : 0.f;
    float sm = ex;
#pragma unroll
    for (int o = 32; o > 0; o >>= 1) sm += __shfl_xor(sm, o, 64);
    float ls = logf(sm);
    if (act) out[(long long)n * OUT_DIM + lane] = v - m - ls;
}

extern "C" void kernel_launch(void* const* d_in, const int* in_sizes, int n_in,
                              void* d_out, int out_size, void* d_ws, size_t ws_size,
                              hipStream_t stream) {
    const float* x   = (const float*)d_in[0];
    const int*   ei  = (const int*)d_in[1];
    const float* Wl1 = (const float*)d_in[2];
    const float* bl1 = (const float*)d_in[3];
    const float* Wr1 = (const float*)d_in[4];
    const float* Wl2 = (const float*)d_in[5];
    const float* bl2 = (const float*)d_in[6];
    const float* Wr2 = (const float*)d_in[7];
    const float* Wl3 = (const float*)d_in[8];
    const float* bl3 = (const float*)d_in[9];
    const float* Wr3 = (const float*)d_in[10];
    float* out = (float*)d_out;

    const int N = in_sizes[0] / IN_DIM;  // 50000
    const int E = in_sizes[1] / 2;       // 600000
    const int* src = ei;
    const int* dst = ei + E;

    // ---- workspace layout ----
    char* w = (char*)d_ws;
    size_t off = 0;
    auto alloc = [&](size_t bytes) {
        void* p = w + off;
        off = (off + bytes + 255) & ~(size_t)255;
        return p;
    };
    ushort* xb   = (ushort*)alloc((size_t)N * IN_DIM * 2);
    ushort* M    = (ushort*)alloc((size_t)N * HID_DIM * 2);
    ushort* H1   = (ushort*)alloc((size_t)N * HID_DIM * 2);
    ushort* H2   = (ushort*)alloc((size_t)N * HID_DIM * 2);
    ushort* P3   = (ushort*)alloc((size_t)N * OUT_DIM * 2);
    float*  S3   = (float*)alloc((size_t)N * OUT_DIM * 4);
    float*  inv  = (float*)alloc((size_t)N * 4);
    int*    cnt  = (int*)alloc((size_t)N * 4);
    int*    rowptr = (int*)alloc((size_t)(N + 1) * 4);
    int*    cursor = (int*)alloc((size_t)N * 4);
    int*    srcs = (int*)alloc((size_t)E * 4);
    int*    bsum = (int*)alloc(256 * 4);
    ushort* Wl1b = (ushort*)alloc(256 * 128 * 2);
    ushort* Wr1b = (ushort*)alloc(256 * 128 * 2);
    ushort* Wl2b = (ushort*)alloc(256 * 256 * 2);
    ushort* Wr2b = (ushort*)alloc(256 * 256 * 2);
    ushort* Wl3b = (ushort*)alloc(48 * 256 * 2);
    ushort* Wr3b = (ushort*)alloc(48 * 256 * 2);
    (void)alloc(64 * 1024);  // guard slack: layer-1 A-stage may read past N

    // ---- prep: cvt_x + cvt_weights(frag-packed) + hist in one launch ----
    const int n4 = N * IN_DIM / 4;
    const int XB = (n4 + 255) / 256;
    const int WB = (32768 + 65536 + 48 * 256 + 255) / 256;
    const int HB = (E + 255) / 256;
    hipMemsetAsync(cnt, 0, (size_t)N * sizeof(int), stream);
    prep_kernel<<<XB + WB + HB, 256, 0, stream>>>(
        x, xb, n4, XB,
        Wl1, Wr1, Wl2, Wr2, Wl3, Wr3,
        Wl1b, Wr1b, Wl2b, Wr2b, Wl3b, Wr3b, WB,
        dst, cnt, E);

    // ---- CSR scan + fill ----
    const int SB = (N + SCAN_CHUNK - 1) / SCAN_CHUNK;  // 25
    scan_pass1<<<SB, 256, 0, stream>>>(cnt, bsum, N);
    scan_pass3<<<SB, 256, 0, stream>>>(cnt, bsum, rowptr, cursor, inv, N, E, SB);
    fill_kernel<<<HB, 256, 0, stream>>>(src, dst, cursor, srcs, E);

    const int gmr = (N + 127) / 128;   // 391 row-tiles of 128 rows (layer-1)
    const int G1 = 2 * gmr;            // 782
    const int gm2 = (N + 255) / 256;   // 196 row-tiles of 256 rows (layer-2)
    const int G2 = 4 * gm2;            // 784
    const int gg128 = (N + 15) / 16;
    const int gg256 = (N + 7) / 8;
    const int gg = (N + 3) / 4;

    // ---- layer 1: K=128 -> 256, relu (LDS-A structure: measured faster) ----
    gather_mean_bf<IN_DIM><<<gg128, 256, 0, stream>>>(xb, rowptr, srcs, inv, M, N);
    sage_gemm_ldsA<IN_DIM, true, true><<<G1, 512, 0, stream>>>(
        M, xb, Wl1b, bl1, Wr1b, H1, N, HID_DIM, G1);

    // ---- layer 2: K=256 -> 256, relu (R17 structure: measured best at K=256) ----
    gather_mean_bf<HID_DIM><<<gg256, 256, 0, stream>>>(H1, rowptr, srcs, inv, M, N);
    sage_gemm_r17<HID_DIM, true, true><<<G2, 512, 0, stream>>>(
        M, H1, Wl2b, bl2, Wr2b, H2, N, HID_DIM, G2);

    // ---- layer 3 (GEMM-first): P3 = H2@Wl3^T, S3 = H2@Wr3^T, then fused agg+lsm ----
    sage_gemm_pre<HID_DIM><<<(N + 63) / 64, 256, 0, stream>>>(
        H2, Wl3b, Wr3b, P3, S3, N, OUT_DIM);
    agg_bias_lsm<<<gg, 256, 0, stream>>>(P3, S3, bl3, rowptr, srcs, inv, out, N);
}

// Round 12
// 337.304 us; speedup vs baseline: 1.0241x; 1.0039x over previous
//
#include <hip/hip_runtime.h>
#include <hip/hip_bf16.h>

#define IN_DIM 128
#define HID_DIM 256
#define OUT_DIM 40
#define SCAN_CHUNK 2048

typedef __attribute__((ext_vector_type(8))) __bf16 bf16x8;
typedef __attribute__((ext_vector_type(4))) float f32x4;

__device__ inline ushort f2bf(float f) {
    uint u = __builtin_bit_cast(uint, f);
    u = (u + 0x7fff + ((u >> 16) & 1)) >> 16;
    return (ushort)u;
}
__device__ inline float bfl(uint u) { return __builtin_bit_cast(float, u << 16); }
__device__ inline float bfh(uint u) { return __builtin_bit_cast(float, u & 0xffff0000u); }

// async global->LDS, 16B per lane. dest base must be wave-uniform; HW adds lane*16.
// The GLOBAL source may be per-lane (m173) — used for the A-swizzle staging.
__device__ inline void gload_lds16(const ushort* g, ushort* l) {
    __builtin_amdgcn_global_load_lds((const __attribute__((address_space(1))) void*)g,
                                     (__attribute__((address_space(3))) void*)l, 16, 0, 0);
}

// bijective XCD-chunked swizzle (m204)
__device__ inline int xcd_swizzle(int b, int G) {
    int q = G >> 3, r = G & 7;
    int xcd = b & 7, j = b >> 3;
    return (xcd < r ? xcd * (q + 1) : r * (q + 1) + (xcd - r) * q) + j;
}

// ---------------- fused prep: cvt_x + cvt_weights + hist (independent jobs) ----------------
__global__ __launch_bounds__(256) void prep_kernel(
    const float* __restrict__ x, ushort* __restrict__ xb, int n4, int XB,
    const float* __restrict__ Wl1, const float* __restrict__ Wr1,
    const float* __restrict__ Wl2, const float* __restrict__ Wr2,
    const float* __restrict__ Wl3, const float* __restrict__ Wr3,
    ushort* __restrict__ o1l, ushort* __restrict__ o1r,
    ushort* __restrict__ o2l, ushort* __restrict__ o2r,
    ushort* __restrict__ o3l, ushort* __restrict__ o3r, int WB,
    const int* __restrict__ dst, int* __restrict__ cnt, int E) {
    int b = blockIdx.x;
    if (b < XB) {
        int i = b * 256 + threadIdx.x;
        if (i < n4) {
            float4 v = ((const float4*)x)[i];
            uint2 o;
            o.x = (uint)f2bf(v.x) | ((uint)f2bf(v.y) << 16);
            o.y = (uint)f2bf(v.z) | ((uint)f2bf(v.w) << 16);
            ((uint2*)xb)[i] = o;
        }
        return;
    }
    b -= XB;
    if (b < WB) {
        int idx = b * 256 + threadIdx.x;
        if (idx < 32768) {
            // W1: K=128, NK=4. idx bits: j3 | ln4 | quad2 | kk2 | ct2 | cb2
            int j = idx & 7, ln = (idx >> 3) & 15, quad = (idx >> 7) & 3;
            int kk = (idx >> 9) & 3, ct = (idx >> 11) & 3, cb = idx >> 13;
            int o = cb * 64 + ct * 16 + ln;
            int k = kk * 32 + quad * 8 + j;
            o1l[idx] = f2bf(Wl1[o * 128 + k]);
            o1r[idx] = f2bf(Wr1[o * 128 + k]);
            return;
        }
        idx -= 32768;
        if (idx < 65536) {
            // W2: K=256, NK=8. idx bits: j3 | ln4 | quad2 | kk3 | ct2 | cb2
            int j = idx & 7, ln = (idx >> 3) & 15, quad = (idx >> 7) & 3;
            int kk = (idx >> 9) & 7, ct = (idx >> 12) & 3, cb = idx >> 14;
            int o = cb * 64 + ct * 16 + ln;
            int k = kk * 32 + quad * 8 + j;
            o2l[idx] = f2bf(Wl2[o * 256 + k]);
            o2r[idx] = f2bf(Wr2[o * 256 + k]);
            return;
        }
        idx -= 65536;
        if (idx < 48 * 256) {
            int row = idx >> 8;
            int col = idx & 255;
            ushort vl = 0, vr = 0;
            if (row < OUT_DIM) {
                vl = f2bf(Wl3[row * 256 + col]);
                vr = f2bf(Wr3[row * 256 + col]);
            }
            o3l[idx] = vl;
            o3r[idx] = vr;
        }
        return;
    }
    b -= WB;
    int e = b * 256 + threadIdx.x;
    if (e < E) atomicAdd(&cnt[dst[e]], 1);
}

// ---------------- CSR scan ----------------
__global__ __launch_bounds__(256) void scan_pass1(const int* __restrict__ cnt,
                                                  int* __restrict__ bsum, int N) {
    __shared__ int red[256];
    const int base = blockIdx.x * SCAN_CHUNK;
    int s = 0;
    for (int i = threadIdx.x; i < SCAN_CHUNK; i += 256) {
        int idx = base + i;
        if (idx < N) s += cnt[idx];
    }
    red[threadIdx.x] = s;
    __syncthreads();
    for (int o = 128; o > 0; o >>= 1) {
        if (threadIdx.x < o) red[threadIdx.x] += red[threadIdx.x + o];
        __syncthreads();
    }
    if (threadIdx.x == 0) bsum[blockIdx.x] = red[0];
}

__global__ __launch_bounds__(256) void scan_pass3(const int* __restrict__ cnt,
                                                  const int* __restrict__ bsum,
                                                  int* __restrict__ rowptr,
                                                  int* __restrict__ cursor,
                                                  float* __restrict__ inv,
                                                  int N, int E, int SB) {
    __shared__ int ls[256];
    __shared__ int boff;
    if (threadIdx.x == 0) {
        int r = 0;
        for (int i = 0; i < blockIdx.x; ++i) r += bsum[i];
        boff = r;
    }
    const int tbase = blockIdx.x * SCAN_CHUNK + threadIdx.x * 8;
    int c[8];
    int s = 0;
#pragma unroll
    for (int j = 0; j < 8; ++j) {
        int idx = tbase + j;
        c[j] = (idx < N) ? cnt[idx] : 0;
        s += c[j];
    }
    ls[threadIdx.x] = s;
    __syncthreads();
    for (int o = 1; o < 256; o <<= 1) {
        int u = (threadIdx.x >= o) ? ls[threadIdx.x - o] : 0;
        __syncthreads();
        ls[threadIdx.x] += u;
        __syncthreads();
    }
    int run = boff + ls[threadIdx.x] - s;
#pragma unroll
    for (int j = 0; j < 8; ++j) {
        int idx = tbase + j;
        if (idx < N) {
            rowptr[idx] = run;
            cursor[idx] = run;
            inv[idx] = 1.0f / fmaxf((float)c[j], 1.0f);
            run += c[j];
        }
    }
    if (blockIdx.x == 0 && threadIdx.x == 0) rowptr[N] = E;
}

__global__ __launch_bounds__(256) void fill_kernel(const int* __restrict__ src,
                                                   const int* __restrict__ dst,
                                                   int* __restrict__ cursor,
                                                   int* __restrict__ srcs, int E) {
    int e = blockIdx.x * 256 + threadIdx.x;
    if (e < E) {
        int pos = atomicAdd(&cursor[dst[e]], 1);
        srcs[pos] = src[e];
    }
}

// ---------------- gather mean (R24: multi-node/wave, 16B/lane, 8-deep ILP) ----------------
template <int D>
__global__ __launch_bounds__(256) void gather_mean_bf(const ushort* __restrict__ feat,
                                                      const int* __restrict__ rowptr,
                                                      const int* __restrict__ srcs,
                                                      const float* __restrict__ inv,
                                                      ushort* __restrict__ out, int N) {
    constexpr int LPN = D / 8;       // lanes per node (16B per lane)
    constexpr int NPW = 64 / LPN;    // nodes per wave: 2 (D=256) or 4 (D=128)
    constexpr int NPB = 4 * NPW;     // nodes per block
    const int wave = threadIdx.x >> 6;
    const int lane = threadIdx.x & 63;
    const int sub = lane / LPN;
    const int sl = lane % LPN;
    const int n = blockIdx.x * NPB + wave * NPW + sub;
    const bool alive = n < N;
    const int beg = alive ? rowptr[n] : 0;
    const int end = alive ? rowptr[n + 1] : 0;
    const int col = sl * 8;

    float a0 = 0.f, a1 = 0.f, a2 = 0.f, a3 = 0.f;
    float a4 = 0.f, a5 = 0.f, a6 = 0.f, a7 = 0.f;
    int e = beg;
    for (; e + 7 < end; e += 8) {
        uint4 q[8];
#pragma unroll
        for (int j = 0; j < 8; ++j)
            q[j] = *(const uint4*)&feat[(long long)srcs[e + j] * D + col];
#pragma unroll
        for (int j = 0; j < 8; ++j) {
            a0 += bfl(q[j].x); a1 += bfh(q[j].x);
            a2 += bfl(q[j].y); a3 += bfh(q[j].y);
            a4 += bfl(q[j].z); a5 += bfh(q[j].z);
            a6 += bfl(q[j].w); a7 += bfh(q[j].w);
        }
    }
    for (; e + 3 < end; e += 4) {
        uint4 q[4];
#pragma unroll
        for (int j = 0; j < 4; ++j)
            q[j] = *(const uint4*)&feat[(long long)srcs[e + j] * D + col];
#pragma unroll
        for (int j = 0; j < 4; ++j) {
            a0 += bfl(q[j].x); a1 += bfh(q[j].x);
            a2 += bfl(q[j].y); a3 += bfh(q[j].y);
            a4 += bfl(q[j].z); a5 += bfh(q[j].z);
            a6 += bfl(q[j].w); a7 += bfh(q[j].w);
        }
    }
    for (; e < end; ++e) {
        uint4 q = *(const uint4*)&feat[(long long)srcs[e] * D + col];
        a0 += bfl(q.x); a1 += bfh(q.x);
        a2 += bfl(q.y); a3 += bfh(q.y);
        a4 += bfl(q.z); a5 += bfh(q.z);
        a6 += bfl(q.w); a7 += bfh(q.w);
    }
    if (alive) {
        const float sc = inv[n];
        uint4 o;
        o.x = (uint)f2bf(a0 * sc) | ((uint)f2bf(a1 * sc) << 16);
        o.y = (uint)f2bf(a2 * sc) | ((uint)f2bf(a3 * sc) << 16);
        o.z = (uint)f2bf(a4 * sc) | ((uint)f2bf(a5 * sc) << 16);
        o.w = (uint)f2bf(a6 * sc) | ((uint)f2bf(a7 * sc) << 16);
        *(uint4*)&out[(long long)n * D + col] = o;
    }
}

// ---------------- LAYER-1 GEMM (R22 LDS-A structure: measured win at K=128, 64KB LDS) ----
template <int K, bool RELU, bool OUTBF>
__global__ __launch_bounds__(512, 4) void sage_gemm_ldsA(const ushort* __restrict__ Amean,
                                                         const ushort* __restrict__ Aself,
                                                         const ushort* __restrict__ Wl,
                                                         const float* __restrict__ bias,
                                                         const ushort* __restrict__ Wr,
                                                         void* __restrict__ outv, int N, int O,
                                                         int G) {
    constexpr int NKK = K / 32;            // k-steps
    constexpr int RB = 2 * K;              // bytes per A row
    constexpr int LOGRB = (K == 256) ? 9 : 8;
    constexpr int TILE64 = 64 * K;         // ushorts per 64-col W group
    constexpr int AC = (128 * RB) / 1024;  // A 1KB chunks
    constexpr int WC = (2 * TILE64 * 2) / 1024;  // W 1KB chunks
    __shared__ __align__(16) ushort As[128 * K];
    __shared__ __align__(16) ushort Wsh[2 * TILE64];

    const int tid = threadIdx.x;
    const int wave = tid >> 6;   // 0..7
    const int lane = tid & 63;
    const int ln = lane & 15;
    const int quad = lane >> 4;

    const int wid = xcd_swizzle(blockIdx.x, G);
    const int c2 = wid & 1;            // 128-col half
    const int bm0 = (wid >> 1) * 128;  // row-block (128 rows: 8 waves x 16)

    f32x4 acc[8] = {};

#pragma unroll
    for (int p = 0; p < 2; ++p) {
        const ushort* __restrict__ A = (p ? Aself : Amean) + (size_t)bm0 * K;
        const ushort* __restrict__ Wg = (p ? Wr : Wl) + (size_t)c2 * 2 * TILE64;

        if (p) __syncthreads();  // all waves done reading phase-0 LDS

#pragma unroll
        for (int c = wave; c < WC; c += 8)
            gload_lds16(Wg + c * 512 + lane * 8, &Wsh[c * 512]);

#pragma unroll
        for (int c = wave; c < AC; c += 8) {
            int q = c * 1024 + lane * 16;           // linear LDS byte pos (this lane)
            int row = q >> LOGRB;
            int inrow = q & (RB - 1);
            int srcb = (row << LOGRB) + (inrow ^ ((row & 7) << 4));
            gload_lds16(A + (srcb >> 1), &As[c * 512]);
        }

        __syncthreads();  // drains vmcnt(0): both stages complete

#pragma unroll
        for (int kk = 0; kk < NKK; ++kk) {
            bf16x8 a = *(const bf16x8*)&As[((wave * 16 + ln) * RB +
                                            ((kk * 64 + quad * 16) ^ ((ln & 7) << 4))) >> 1];
#pragma unroll
            for (int ct = 0; ct < 8; ++ct) {
                bf16x8 b = *(const bf16x8*)&Wsh[(ct >> 2) * TILE64 + (((ct & 3) * NKK + kk) * 64 + lane) * 8];
                acc[ct] = __builtin_amdgcn_mfma_f32_16x16x32_bf16(a, b, acc[ct], 0, 0, 0);
            }
        }
    }

    {
        int rbase = bm0 + wave * 16 + quad * 4;
#pragma unroll
        for (int ct = 0; ct < 8; ++ct) {
            int col = c2 * 128 + ct * 16 + ln;
            if (col >= O) continue;
            float bv = bias[col];
#pragma unroll
            for (int r = 0; r < 4; ++r) {
                int row = rbase + r;
                if (row >= N) continue;
                float v = acc[ct][r] + bv;
                if (RELU) v = fmaxf(v, 0.f);
                if (OUTBF)
                    ((ushort*)outv)[(long long)row * O + col] = f2bf(v);
                else
                    ((float*)outv)[(long long)row * O + col] = v;
            }
        }
    }
}

// ---------------- LAYER-2 GEMM (R17 structure: measured best 46.2us at K=256) ------------
template <int K, bool RELU, bool OUTBF>
__global__ __launch_bounds__(512, 4) void sage_gemm_r17(const ushort* __restrict__ Amean,
                                                        const ushort* __restrict__ Aself,
                                                        const ushort* __restrict__ Wl,
                                                        const float* __restrict__ bias,
                                                        const ushort* __restrict__ Wr,
                                                        void* __restrict__ outv, int N, int O,
                                                        int G) {
    constexpr int NK = K / 32;            // k-steps per phase
    constexpr int TILE = 64 * K;          // ushorts per (cb, matrix) W tile
    constexpr int CHUNKS = TILE / 512;    // 1KB chunks
    __shared__ __align__(16) ushort Ws[2 * TILE];  // K=256: 64KB

    const int tid = threadIdx.x;
    const int wave = tid >> 6;   // 0..7
    const int lane = tid & 63;
    const int ln = lane & 15;
    const int quad = lane >> 4;

    const int wid = xcd_swizzle(blockIdx.x, G);
    const int cb = wid & 3;            // col-block: fast axis within an XCD chunk
    const int bm0 = (wid >> 2) * 256;  // row-block (256 rows: 8 waves x 32)

    {
        const ushort* gl = Wl + (size_t)cb * TILE;
        const ushort* gr = Wr + (size_t)cb * TILE;
#pragma unroll
        for (int c = wave; c < CHUNKS; c += 8) {
            gload_lds16(gl + c * 512 + lane * 8, &Ws[c * 512]);
            gload_lds16(gr + c * 512 + lane * 8, &Ws[TILE + c * 512]);
        }
    }

    int arow[2];
#pragma unroll
    for (int rt = 0; rt < 2; ++rt) {
        int r = bm0 + wave * 32 + rt * 16 + ln;
        arow[rt] = min(r, N - 1);
    }

    bf16x8 areg[NK][2];
#pragma unroll
    for (int kk = 0; kk < NK; ++kk)
#pragma unroll
        for (int rt = 0; rt < 2; ++rt)
            areg[kk][rt] = *(const bf16x8*)&Amean[(long long)arow[rt] * K + kk * 32 + quad * 8];

    f32x4 acc[2][4] = {};
    __syncthreads();  // ONE barrier: drains gll + phase-0 areg

#pragma unroll
    for (int kk = 0; kk < NK; ++kk) {
#pragma unroll
        for (int ct = 0; ct < 4; ++ct) {
            bf16x8 b = *(const bf16x8*)&Ws[((ct * NK + kk) * 64 + lane) * 8];
#pragma unroll
            for (int rt = 0; rt < 2; ++rt)
                acc[rt][ct] = __builtin_amdgcn_mfma_f32_16x16x32_bf16(areg[kk][rt], b, acc[rt][ct], 0, 0, 0);
        }
#pragma unroll
        for (int rt = 0; rt < 2; ++rt)
            areg[kk][rt] = *(const bf16x8*)&Aself[(long long)arow[rt] * K + kk * 32 + quad * 8];
    }

#pragma unroll
    for (int kk = 0; kk < NK; ++kk) {
#pragma unroll
        for (int ct = 0; ct < 4; ++ct) {
            bf16x8 b = *(const bf16x8*)&Ws[TILE + ((ct * NK + kk) * 64 + lane) * 8];
#pragma unroll
            for (int rt = 0; rt < 2; ++rt)
                acc[rt][ct] = __builtin_amdgcn_mfma_f32_16x16x32_bf16(areg[kk][rt], b, acc[rt][ct], 0, 0, 0);
        }
    }

#pragma unroll
    for (int rt = 0; rt < 2; ++rt) {
        int rbase = bm0 + wave * 32 + rt * 16 + quad * 4;
#pragma unroll
        for (int ct = 0; ct < 4; ++ct) {
            int col = cb * 64 + ct * 16 + ln;
            if (col >= O) continue;
            float bv = bias[col];
#pragma unroll
            for (int r = 0; r < 4; ++r) {
                int row = rbase + r;
                if (row >= N) continue;
                float v = acc[rt][ct][r] + bv;
                if (RELU) v = fmaxf(v, 0.f);
                if (OUTBF)
                    ((ushort*)outv)[(long long)row * O + col] = f2bf(v);
                else
                    ((float*)outv)[(long long)row * O + col] = v;
            }
        }
    }
}

// ---------------- layer-3 pre-aggregation GEMM: P = A@Wl^T (bf16), S = A@Wr^T (fp32) ----------------
template <int K>
__global__ __launch_bounds__(256, 3) void sage_gemm_pre(const ushort* __restrict__ A0,
                                                        const ushort* __restrict__ Wl,
                                                        const ushort* __restrict__ Wr,
                                                        ushort* __restrict__ P,
                                                        float* __restrict__ S, int N, int O) {
    constexpr int KP = 2 * K + 8;
    constexpr int NK = K / 32;  // 8
    __shared__ __align__(16) ushort Ws[48 * KP];  // 49 KB

    const int tid = threadIdx.x;
    const int wave = tid >> 6;
    const int lane = tid & 63;
    const int ln = lane & 15;
    const int quad = lane >> 4;
    const int bm0 = blockIdx.x * 64;

    const int arow = min(bm0 + wave * 16 + ln, N - 1);

#pragma unroll
    for (int i = tid; i < 48 * (K / 8); i += 256) {
        int row = i / (K / 8);
        int c8 = (i % (K / 8)) * 8;
        *(ulonglong2*)&Ws[row * KP + c8] =
            *(const ulonglong2*)&Wl[(long long)row * K + c8];
        *(ulonglong2*)&Ws[row * KP + K + c8] =
            *(const ulonglong2*)&Wr[(long long)row * K + c8];
    }
    __syncthreads();

#pragma unroll
    for (int phase = 0; phase < 2; ++phase) {
        f32x4 acc[3] = {};
#pragma unroll
        for (int kk = 0; kk < NK; ++kk) {
            bf16x8 a = *(const bf16x8*)&A0[(long long)arow * K + kk * 32 + quad * 8];
#pragma unroll
            for (int ct = 0; ct < 3; ++ct) {
                bf16x8 b = *(const bf16x8*)&Ws[(ct * 16 + ln) * KP + phase * K + kk * 32 + quad * 8];
                acc[ct] = __builtin_amdgcn_mfma_f32_16x16x32_bf16(a, b, acc[ct], 0, 0, 0);
            }
        }
        int rbase = bm0 + wave * 16 + quad * 4;
#pragma unroll
        for (int ct = 0; ct < 3; ++ct) {
            int col = ct * 16 + ln;
            if (col >= O) continue;
#pragma unroll
            for (int r = 0; r < 4; ++r) {
                int row = rbase + r;
                if (row >= N) continue;
                if (phase == 0)
                    P[(long long)row * O + col] = f2bf(acc[ct][r]);
                else
                    S[(long long)row * O + col] = acc[ct][r];
            }
        }
    }
}

// ---------------- fused mean-agg(D=40) + self + bias + log_softmax (R24: 8-deep ILP) -----
__global__ __launch_bounds__(256) void agg_bias_lsm(const ushort* __restrict__ P,
                                                    const float* __restrict__ S,
                                                    const float* __restrict__ bias,
                                                    const int* __restrict__ rowptr,
                                                    const int* __restrict__ srcs,
                                                    const float* __restrict__ inv,
                                                    float* __restrict__ out, int N) {
    const int wave = threadIdx.x >> 6;
    const int lane = threadIdx.x & 63;
    const int n = blockIdx.x * 4 + wave;
    if (n >= N) return;
    const int beg = rowptr[n];
    const int end = rowptr[n + 1];
    const bool act = lane < OUT_DIM;
    const int cidx = act ? lane : 0;

    float acc = 0.f;
    int e = beg;
    for (; e + 7 < end; e += 8) {
        float v[8];
#pragma unroll
        for (int j = 0; j < 8; ++j)
            v[j] = __builtin_bit_cast(float, (uint)P[(long long)srcs[e + j] * OUT_DIM + cidx] << 16);
        acc += ((v[0] + v[1]) + (v[2] + v[3])) + ((v[4] + v[5]) + (v[6] + v[7]));
    }
    for (; e + 3 < end; e += 4) {
        float v0 = __builtin_bit_cast(float, (uint)P[(long long)srcs[e] * OUT_DIM + cidx] << 16);
        float v1 = __builtin_bit_cast(float, (uint)P[(long long)srcs[e + 1] * OUT_DIM + cidx] << 16);
        float v2 = __builtin_bit_cast(float, (uint)P[(long long)srcs[e + 2] * OUT_DIM + cidx] << 16);
        float v3 = __builtin_bit_cast(float, (uint)P[(long long)srcs[e + 3] * OUT_DIM + cidx] << 16);
        acc += (v0 + v1) + (v2 + v3);
    }
    for (; e < end; ++e)
        acc += __builtin_bit_cast(float, (uint)P[(long long)srcs[e] * OUT_DIM + cidx] << 16);

    float v = act ? (acc * inv[n] + S[(long long)n * OUT_DIM + lane] + bias[lane]) : -INFINITY;
    float m = v;
#pragma unroll
    for (int o = 32; o > 0; o >>= 1) m = fmaxf(m, __shfl_xor(m, o, 64));
    float ex = act ? expf(v - m) : 0.f;
    float sm = ex;
#pragma unroll
    for (int o = 32; o > 0; o >>= 1) sm += __shfl_xor(sm, o, 64);
    float ls = logf(sm);
    if (act) out[(long long)n * OUT_DIM + lane] = v - m - ls;
}

extern "C" void kernel_launch(void* const* d_in, const int* in_sizes, int n_in,
                              void* d_out, int out_size, void* d_ws, size_t ws_size,
                              hipStream_t stream) {
    const float* x   = (const float*)d_in[0];
    const int*   ei  = (const int*)d_in[1];
    const float* Wl1 = (const float*)d_in[2];
    const float* bl1 = (const float*)d_in[3];
    const float* Wr1 = (const float*)d_in[4];
    const float* Wl2 = (const float*)d_in[5];
    const float* bl2 = (const float*)d_in[6];
    const float* Wr2 = (const float*)d_in[7];
    const float* Wl3 = (const float*)d_in[8];
    const float* bl3 = (const float*)d_in[9];
    const float* Wr3 = (const float*)d_in[10];
    float* out = (float*)d_out;

    const int N = in_sizes[0] / IN_DIM;  // 50000
    const int E = in_sizes[1] / 2;       // 600000
    const int* src = ei;
    const int* dst = ei + E;

    // ---- workspace layout ----
    char* w = (char*)d_ws;
    size_t off = 0;
    auto alloc = [&](size_t bytes) {
        void* p = w + off;
        off = (off + bytes + 255) & ~(size_t)255;
        return p;
    };
    ushort* xb   = (ushort*)alloc((size_t)N * IN_DIM * 2);
    ushort* M    = (ushort*)alloc((size_t)N * HID_DIM * 2);
    ushort* H1   = (ushort*)alloc((size_t)N * HID_DIM * 2);
    ushort* H2   = (ushort*)alloc((size_t)N * HID_DIM * 2);
    ushort* P3   = (ushort*)alloc((size_t)N * OUT_DIM * 2);
    float*  S3   = (float*)alloc((size_t)N * OUT_DIM * 4);
    float*  inv  = (float*)alloc((size_t)N * 4);
    int*    cnt  = (int*)alloc((size_t)N * 4);
    int*    rowptr = (int*)alloc((size_t)(N + 1) * 4);
    int*    cursor = (int*)alloc((size_t)N * 4);
    int*    srcs = (int*)alloc((size_t)E * 4);
    int*    bsum = (int*)alloc(256 * 4);
    ushort* Wl1b = (ushort*)alloc(256 * 128 * 2);
    ushort* Wr1b = (ushort*)alloc(256 * 128 * 2);
    ushort* Wl2b = (ushort*)alloc(256 * 256 * 2);
    ushort* Wr2b = (ushort*)alloc(256 * 256 * 2);
    ushort* Wl3b = (ushort*)alloc(48 * 256 * 2);
    ushort* Wr3b = (ushort*)alloc(48 * 256 * 2);
    (void)alloc(64 * 1024);  // guard slack: layer-1 A-stage may read past N

    // ---- prep: cvt_x + cvt_weights(frag-packed) + hist in one launch ----
    const int n4 = N * IN_DIM / 4;
    const int XB = (n4 + 255) / 256;
    const int WB = (32768 + 65536 + 48 * 256 + 255) / 256;
    const int HB = (E + 255) / 256;
    hipMemsetAsync(cnt, 0, (size_t)N * sizeof(int), stream);
    prep_kernel<<<XB + WB + HB, 256, 0, stream>>>(
        x, xb, n4, XB,
        Wl1, Wr1, Wl2, Wr2, Wl3, Wr3,
        Wl1b, Wr1b, Wl2b, Wr2b, Wl3b, Wr3b, WB,
        dst, cnt, E);

    // ---- CSR scan + fill ----
    const int SB = (N + SCAN_CHUNK - 1) / SCAN_CHUNK;  // 25
    scan_pass1<<<SB, 256, 0, stream>>>(cnt, bsum, N);
    scan_pass3<<<SB, 256, 0, stream>>>(cnt, bsum, rowptr, cursor, inv, N, E, SB);
    fill_kernel<<<HB, 256, 0, stream>>>(src, dst, cursor, srcs, E);

    const int gmr = (N + 127) / 128;   // 391 row-tiles of 128 rows (layer-1)
    const int G1 = 2 * gmr;            // 782
    const int gm2 = (N + 255) / 256;   // 196 row-tiles of 256 rows (layer-2)
    const int G2 = 4 * gm2;            // 784
    const int gg128 = (N + 15) / 16;
    const int gg256 = (N + 7) / 8;
    const int gg = (N + 3) / 4;

    // ---- layer 1: K=128 -> 256, relu (LDS-A structure: measured faster) ----
    gather_mean_bf<IN_DIM><<<gg128, 256, 0, stream>>>(xb, rowptr, srcs, inv, M, N);
    sage_gemm_ldsA<IN_DIM, true, true><<<G1, 512, 0, stream>>>(
        M, xb, Wl1b, bl1, Wr1b, H1, N, HID_DIM, G1);

    // ---- layer 2: K=256 -> 256, relu (R17 structure: measured best at K=256) ----
    gather_mean_bf<HID_DIM><<<gg256, 256, 0, stream>>>(H1, rowptr, srcs, inv, M, N);
    sage_gemm_r17<HID_DIM, true, true><<<G2, 512, 0, stream>>>(
        M, H1, Wl2b, bl2, Wr2b, H2, N, HID_DIM, G2);

    // ---- layer 3 (GEMM-first): P3 = H2@Wl3^T, S3 = H2@Wr3^T, then fused agg+lsm ----
    sage_gemm_pre<HID_DIM><<<(N + 63) / 64, 256, 0, stream>>>(
        H2, Wl3b, Wr3b, P3, S3, N, OUT_DIM);
    agg_bias_lsm<<<gg, 256, 0, stream>>>(P3, S3, bl3, rowptr, srcs, inv, out, N);
}